// Round 14
// baseline (480.193 us; speedup 1.0000x reference)
//
#include <hip/hip_runtime.h>
#include <math.h>

#define NB 64       // batch
#define NS 512      // seq len
#define ND 512      // input dim
#define NH 512      // hidden
#define NC (NS / 8) // 8-step chunks
#define L2E 1.4426950408889634f

// 64-lane sum via DPP (VALU only). Total lands in lane 63.
__device__ __forceinline__ float dpp_sum64(float x) {
    x += __int_as_float(__builtin_amdgcn_update_dpp(0, __float_as_int(x), 0x111, 0xf, 0xf, true)); // row_shr:1
    x += __int_as_float(__builtin_amdgcn_update_dpp(0, __float_as_int(x), 0x112, 0xf, 0xf, true)); // row_shr:2
    x += __int_as_float(__builtin_amdgcn_update_dpp(0, __float_as_int(x), 0x114, 0xf, 0xf, true)); // row_shr:4
    x += __int_as_float(__builtin_amdgcn_update_dpp(0, __float_as_int(x), 0x118, 0xf, 0xf, true)); // row_shr:8
    x += __int_as_float(__builtin_amdgcn_update_dpp(0, __float_as_int(x), 0x142, 0xa, 0xf, true)); // row_bcast:15
    x += __int_as_float(__builtin_amdgcn_update_dpp(0, __float_as_int(x), 0x143, 0xc, 0xf, true)); // row_bcast:31
    return x;
}

__device__ __forceinline__ float bcast63(float x) {
    return __int_as_float(__builtin_amdgcn_readlane(__float_as_int(x), 63));
}
__device__ __forceinline__ float rcp_fast(float x) { return __builtin_amdgcn_rcpf(x); }
__device__ __forceinline__ float exp2_fast(float x) {
    float r;
    asm("v_exp_f32 %0, %1" : "=v"(r) : "v"(x));
    return r;
}
__device__ __forceinline__ void wg_barrier() {
    asm volatile("s_waitcnt lgkmcnt(0)\n\ts_barrier" ::: "memory");
}
__device__ __forceinline__ void full_barrier() {
    asm volatile("s_waitcnt vmcnt(0) lgkmcnt(0)\n\ts_barrier" ::: "memory");
}
__device__ __forceinline__ void spin_on(const unsigned int* p) {
    while (__hip_atomic_load(p, __ATOMIC_ACQUIRE, __HIP_MEMORY_SCOPE_AGENT) == 0) {}
}
__device__ __forceinline__ void release_flag(unsigned int* p) {
    __hip_atomic_store(p, 1u, __ATOMIC_RELEASE, __HIP_MEMORY_SCOPE_AGENT);
}

// dot of an 8-float weight slice against the two h float4s
__device__ __forceinline__ float dot8s(const float* s, float4 x0, float4 x1) {
    float r = s[0] * x0.x;
    r = fmaf(s[1], x0.y, r); r = fmaf(s[2], x0.z, r); r = fmaf(s[3], x0.w, r);
    r = fmaf(s[4], x1.x, r); r = fmaf(s[5], x1.y, r); r = fmaf(s[6], x1.z, r);
    r = fmaf(s[7], x1.w, r);
    return r;
}

// permuted gather of factor row f (LDS slot s holds row 8*(s&63)+(s>>6))
#define LW(mat, f, arr)                                                       \
    {                                                                         \
        const float* M = (mat) + (f) * NH;                                    \
        arr[0] = M[kb];      arr[1] = M[kb + 8];                              \
        arr[2] = M[kb + 16]; arr[3] = M[kb + 24];                             \
        arr[4] = M[kb + 4];  arr[5] = M[kb + 12];                             \
        arr[6] = M[kb + 20]; arr[7] = M[kb + 28];                             \
    }

// one LSTM row update; coefficients pre-scaled by {-L2E,-L2E,+2L2E,-L2E}:
//   sigm -> 1/(1+2^g), tanh -> 1-2/(1+2^g)
#define GATEX(t1, t2, m3, m4, bb, cS, hS)                                     \
    {                                                                         \
        float g0 = fmaf(cw[0], (t1), fmaf(cdw[0], (t2), fmaf(cu[0], (m3), fmaf(cdu[0], (m4), bb[0])))); \
        float g1 = fmaf(cw[1], (t1), fmaf(cdw[1], (t2), fmaf(cu[1], (m3), fmaf(cdu[1], (m4), bb[1])))); \
        float g2 = fmaf(cw[2], (t1), fmaf(cdw[2], (t2), fmaf(cu[2], (m3), fmaf(cdu[2], (m4), bb[2])))); \
        float g3 = fmaf(cw[3], (t1), fmaf(cdw[3], (t2), fmaf(cu[3], (m3), fmaf(cdu[3], (m4), bb[3])))); \
        float ig = rcp_fast(1.0f + exp2_fast(g0));                            \
        float fg = rcp_fast(1.0f + exp2_fast(g1));                            \
        float gg = fmaf(-2.0f, rcp_fast(1.0f + exp2_fast(g2)), 1.0f);         \
        float og = rcp_fast(1.0f + exp2_fast(g3));                            \
        cS = fmaf(fg, cS, ig * gg);                                           \
        hS = og * fmaf(-2.0f, rcp_fast(1.0f + exp2_fast(cS * (2.0f * L2E))), 1.0f); \
    }

// ---------------------------------------------------------------------------
// Kernel A: PT[bt] as 8 x float2: {(W12@x)[g], (dW12@x)[g]} for g = 0..7
// ---------------------------------------------------------------------------
__global__ __launch_bounds__(64) void precomp_kernel(
    const float* __restrict__ x, const float* __restrict__ W12,
    const float* __restrict__ dW12, float* __restrict__ PT) {
    int bt = blockIdx.x;
    int l = threadIdx.x;
    const float4* xr = (const float4*)(x + (size_t)bt * ND);
    float4 xv0 = xr[l];
    float4 xv1 = xr[64 + l];

    float acc[16];
#pragma unroll
    for (int f = 0; f < 8; ++f) {
        const float4* w = (const float4*)(W12 + f * ND);
        float4 a = w[l], b = w[64 + l];
        float s = a.x * xv0.x;
        s = fmaf(a.y, xv0.y, s); s = fmaf(a.z, xv0.z, s); s = fmaf(a.w, xv0.w, s);
        s = fmaf(b.x, xv1.x, s); s = fmaf(b.y, xv1.y, s); s = fmaf(b.z, xv1.z, s);
        s = fmaf(b.w, xv1.w, s);
        acc[f] = s;
        const float4* dw = (const float4*)(dW12 + f * ND);
        float4 c = dw[l], d = dw[64 + l];
        float u = c.x * xv0.x;
        u = fmaf(c.y, xv0.y, u); u = fmaf(c.z, xv0.z, u); u = fmaf(c.w, xv0.w, u);
        u = fmaf(d.x, xv1.x, u); u = fmaf(d.y, xv1.y, u); u = fmaf(d.z, xv1.z, u);
        u = fmaf(d.w, xv1.w, u);
        acc[8 + f] = u;
    }
#pragma unroll
    for (int f = 0; f < 16; ++f) acc[f] = dpp_sum64(acc[f]);

    if (l == 63) {
        float2* o = (float2*)(PT + (size_t)bt * 16);
#pragma unroll
        for (int g = 0; g < 8; ++g) o[g] = make_float2(acc[g], acc[8 + g]);
    }
}

// ---------------------------------------------------------------------------
// Kernel B: 2-CU pipeline per element (128 blocks x 512 threads, 8 waves).
// role 0 (producer): layer-1 recurrence + W22/dW22 projections -> mrecT,
//   chunk flag every 8 steps after a full vmcnt-drain barrier. Never waits
//   on the consumer (mrecT is full-size).
// role 1 (consumer): layer-2 recurrence; per chunk: one acquire spin + one
//   batched register load of the 16 m-floats (zero in-chunk VMEM waits).
// Wave g owns factor g and rows 8l+g; m-values a row needs come from its
// own wave (readlane) -> no cross-wave exchange for gates. One lgkm-only
// barrier per step inside each block.
// ---------------------------------------------------------------------------
__global__ __launch_bounds__(512, 2) void lstm_pipe_kernel(
    const float* __restrict__ PT, const float* __restrict__ h0,
    const float* __restrict__ c0,
    const float* __restrict__ W11, const float* __restrict__ U11,
    const float* __restrict__ dW11, const float* __restrict__ dU11,
    const float* __restrict__ U12, const float* __restrict__ dU12,
    const float* __restrict__ b11, const float* __restrict__ b12,
    const float* __restrict__ W21, const float* __restrict__ U21,
    const float* __restrict__ dW21, const float* __restrict__ dU21,
    const float* __restrict__ W22, const float* __restrict__ dW22,
    const float* __restrict__ U22, const float* __restrict__ dU22,
    const float* __restrict__ b21, const float* __restrict__ b22,
    float* __restrict__ mrecT, unsigned int* __restrict__ flagb,
    float* __restrict__ out) {
    int role = blockIdx.x >> 6;
    int b = blockIdx.x & 63;
    int tid = threadIdx.x;
    int wv = tid >> 6;              // wave = factor g
    int l = tid & 63;
    int g = wv;
    int kb = 32 * (l & 15) + (l >> 4);
    int r = 8 * l + g;              // owned row (slot tid in permuted LDS)

    __shared__ float Ps[NS * 16];   // 32 KB (producer only)
    __shared__ float hb[2][NH];     // state double-buffer (permuted slots)

    float* hn = out + (size_t)NB * NS * NH;
    float* cn = hn + (size_t)2 * NB * NH;
    const float SQ[4] = {-L2E, -L2E, 2.0f * L2E, -L2E};

    if (role == 0) {
        // ======================= PRODUCER (layer 1 + proj) =================
        {
            const float4* src = (const float4*)(PT + (size_t)b * NS * 16);
            float4* dst = (float4*)Ps;
#pragma unroll
            for (int i = 0; i < 4; ++i) dst[tid + i * 512] = src[tid + i * 512];
        }
        float wU[8], wD[8], wW[8], wV[8];
        LW(U12, g, wU)
        LW(dU12, g, wD)
        LW(W22, g, wW)
        LW(dW22, g, wV)

        float cw[4], cdw[4], cu[4], cdu[4], bb[4];
#pragma unroll
        for (int q = 0; q < 4; ++q) {
            cw[q] = W11[q * 64 + l] * SQ[q];
            cdw[q] = dW11[q * 64 + l] * SQ[q];
            cu[q] = U11[q * 64 + l] * SQ[q];
            cdu[q] = dU11[q * 64 + l] * SQ[q];
            bb[q] = (b11[q * NH + r] + b12[q * NH + r]) * SQ[q];
        }
        float hA = h0[(size_t)b * NH + r];
        float cA = c0[(size_t)b * NH + r];
        hb[0][tid] = hA;
        wg_barrier();

        unsigned int* fb = flagb + b * NC;
        for (int i = 0; i <= NS; ++i) {
            float4 x0 = *(const float4*)&hb[i & 1][4 * l];
            float4 x1 = *(const float4*)&hb[i & 1][256 + 4 * l];
            // projections of h1(i) -> record for step i-1 (chunk-major)
            float rW = dpp_sum64(dot8s(wW, x0, x1));
            float rV = dpp_sum64(dot8s(wV, x0, x1));
            if (i > 0 && l == 63) {
                int s = i - 1;
                float* rec = mrecT +
                    ((size_t)(b * NC + (s >> 3)) * 8 + g) * 16 + 2 * (s & 7);
                *(float2*)rec = make_float2(rW, rV);
            }
            if (i < NS) {
                float rU = dpp_sum64(dot8s(wU, x0, x1));
                float rD = dpp_sum64(dot8s(wD, x0, x1));
                float m3 = bcast63(rU), m4 = bcast63(rD);
                float2 pv = *(const float2*)&Ps[i * 16 + 2 * g];
                GATEX(pv.x, pv.y, m3, m4, bb, cA, hA)
                hb[(i + 1) & 1][tid] = hA;
            }
            if ((i & 7) == 0 && i > 0) {
                full_barrier();  // all waves' mrec stores for chunk done
                if (tid == 0) release_flag(&fb[(i >> 3) - 1]);
            } else {
                wg_barrier();
            }
        }
        hn[(size_t)b * NH + r] = hA;
        cn[(size_t)b * NH + r] = cA;
    } else {
        // ========================= CONSUMER (layer 2) ======================
        float wU[8], wD[8];
        LW(U22, g, wU)
        LW(dU22, g, wD)

        float cw[4], cdw[4], cu[4], cdu[4], bb[4];
#pragma unroll
        for (int q = 0; q < 4; ++q) {
            cw[q] = W21[q * 64 + l] * SQ[q];
            cdw[q] = dW21[q * 64 + l] * SQ[q];
            cu[q] = U21[q * 64 + l] * SQ[q];
            cdu[q] = dU21[q * 64 + l] * SQ[q];
            bb[q] = (b21[q * NH + r] + b22[q * NH + r]) * SQ[q];
        }
        float hA = h0[(size_t)NB * NH + (size_t)b * NH + r];
        float cA = c0[(size_t)NB * NH + (size_t)b * NH + r];
        hb[0][tid] = hA;
        wg_barrier();

        const unsigned int* fb = flagb + b * NC;
        float* outb = out + (size_t)b * NS * NH;
        for (int k = 0; k < NC; ++k) {
            spin_on(&fb[k]);
            // batched wave-uniform m-load: this wave's factor, 8 steps
            const float4* rec = (const float4*)(mrecT +
                ((size_t)(b * NC + k) * 8 + g) * 16);
            float4 q0 = rec[0], q1 = rec[1], q2 = rec[2], q3 = rec[3];
            float mq[16] = {q0.x, q0.y, q0.z, q0.w, q1.x, q1.y, q1.z, q1.w,
                            q2.x, q2.y, q2.z, q2.w, q3.x, q3.y, q3.z, q3.w};
#pragma unroll
            for (int j = 0; j < 8; ++j) {
                int s = k * 8 + j;
                float4 y0 = *(const float4*)&hb[s & 1][4 * l];
                float4 y1 = *(const float4*)&hb[s & 1][256 + 4 * l];
                float rU = dpp_sum64(dot8s(wU, y0, y1));
                float rD = dpp_sum64(dot8s(wD, y0, y1));
                float m5 = bcast63(rU), m6 = bcast63(rD);
                GATEX(mq[2 * j], mq[2 * j + 1], m5, m6, bb, cA, hA)
                hb[(s + 1) & 1][tid] = hA;
                outb[(size_t)s * NH + r] = hA;   // fire-and-forget
                wg_barrier();
            }
        }
        hn[(size_t)NB * NH + (size_t)b * NH + r] = hA;
        cn[(size_t)NB * NH + (size_t)b * NH + r] = cA;
    }
}

extern "C" void kernel_launch(void* const* d_in, const int* in_sizes, int n_in,
                              void* d_out, int out_size, void* d_ws, size_t ws_size,
                              hipStream_t stream) {
    const float* x = (const float*)d_in[0];
    const float* h0 = (const float*)d_in[1];
    const float* c0 = (const float*)d_in[2];
    const float* W11 = (const float*)d_in[3];
    const float* W12 = (const float*)d_in[4];
    const float* U11 = (const float*)d_in[5];
    const float* U12 = (const float*)d_in[6];
    const float* dW11 = (const float*)d_in[7];
    const float* dW12 = (const float*)d_in[8];
    const float* dU11 = (const float*)d_in[9];
    const float* dU12 = (const float*)d_in[10];
    const float* b11 = (const float*)d_in[11];
    const float* b12 = (const float*)d_in[12];
    const float* W21 = (const float*)d_in[13];
    const float* W22 = (const float*)d_in[14];
    const float* U21 = (const float*)d_in[15];
    const float* U22 = (const float*)d_in[16];
    const float* dW21 = (const float*)d_in[17];
    const float* dW22 = (const float*)d_in[18];
    const float* dU21 = (const float*)d_in[19];
    const float* dU22 = (const float*)d_in[20];
    const float* b21 = (const float*)d_in[21];
    const float* b22 = (const float*)d_in[22];

    char* ws = (char*)d_ws;
    float* PT = (float*)ws;                                         // 2 MB
    float* mrecT = (float*)(ws + (size_t)2 * 1024 * 1024);          // 2 MB
    unsigned int* flagb = (unsigned int*)(ws + (size_t)4 * 1024 * 1024);  // 16 KB
    float* out = (float*)d_out;

    hipMemsetAsync(flagb, 0, NB * NC * sizeof(unsigned int), stream);
    hipLaunchKernelGGL(precomp_kernel, dim3(NB * NS), dim3(64), 0, stream,
                       x, W12, dW12, PT);
    hipLaunchKernelGGL(lstm_pipe_kernel, dim3(2 * NB), dim3(512), 0, stream,
                       PT, h0, c0,
                       W11, U11, dW11, dU11, U12, dU12, b11, b12,
                       W21, U21, dW21, dU21, W22, dW22, U22, dU22, b21, b22,
                       mrecT, flagb, out);
}

// Round 15
// 442.386 us; speedup vs baseline: 1.0855x; 1.0855x over previous
//
#include <hip/hip_runtime.h>
#include <math.h>

#define NB 64       // batch
#define NS 512      // seq len
#define ND 512      // input dim
#define NH 512      // hidden
#define L2E 1.4426950408889634f

// 64-lane sum via DPP (VALU only). Total lands in lane 63.
__device__ __forceinline__ float dpp_sum64(float x) {
    x += __int_as_float(__builtin_amdgcn_update_dpp(0, __float_as_int(x), 0x111, 0xf, 0xf, true)); // row_shr:1
    x += __int_as_float(__builtin_amdgcn_update_dpp(0, __float_as_int(x), 0x112, 0xf, 0xf, true)); // row_shr:2
    x += __int_as_float(__builtin_amdgcn_update_dpp(0, __float_as_int(x), 0x114, 0xf, 0xf, true)); // row_shr:4
    x += __int_as_float(__builtin_amdgcn_update_dpp(0, __float_as_int(x), 0x118, 0xf, 0xf, true)); // row_shr:8
    x += __int_as_float(__builtin_amdgcn_update_dpp(0, __float_as_int(x), 0x142, 0xa, 0xf, true)); // row_bcast:15
    x += __int_as_float(__builtin_amdgcn_update_dpp(0, __float_as_int(x), 0x143, 0xc, 0xf, true)); // row_bcast:31
    return x;
}

__device__ __forceinline__ float bcast63(float x) {
    return __int_as_float(__builtin_amdgcn_readlane(__float_as_int(x), 63));
}
__device__ __forceinline__ float rcp_fast(float x) { return __builtin_amdgcn_rcpf(x); }
__device__ __forceinline__ float exp2_fast(float x) {
    float r;
    asm("v_exp_f32 %0, %1" : "=v"(r) : "v"(x));
    return r;
}
__device__ __forceinline__ void wg_barrier() {
    asm volatile("s_waitcnt lgkmcnt(0)\n\ts_barrier" ::: "memory");
}

// dot of an 8-float weight slice against the two h float4s
__device__ __forceinline__ float dot8s(const float* s, float4 x0, float4 x1) {
    float r = s[0] * x0.x;
    r = fmaf(s[1], x0.y, r); r = fmaf(s[2], x0.z, r); r = fmaf(s[3], x0.w, r);
    r = fmaf(s[4], x1.x, r); r = fmaf(s[5], x1.y, r); r = fmaf(s[6], x1.z, r);
    r = fmaf(s[7], x1.w, r);
    return r;
}

// permuted gather of factor row f (LDS slot s holds row 8*(s&63)+(s>>6))
#define LW(mat, f, arr)                                                       \
    {                                                                         \
        const float* M = (mat) + (f) * NH;                                    \
        arr[0] = M[kb];      arr[1] = M[kb + 8];                              \
        arr[2] = M[kb + 16]; arr[3] = M[kb + 24];                             \
        arr[4] = M[kb + 4];  arr[5] = M[kb + 12];                             \
        arr[6] = M[kb + 20]; arr[7] = M[kb + 28];                             \
    }

// one LSTM row update; coefficients pre-scaled by {-L2E,-L2E,+2L2E,-L2E}:
//   sigm -> 1/(1+2^g), tanh -> 1-2/(1+2^g)
#define GATEX(t1, t2, m3, m4, bb, cS, hS)                                     \
    {                                                                         \
        float g0 = fmaf(cw[0], (t1), fmaf(cdw[0], (t2), fmaf(cu[0], (m3), fmaf(cdu[0], (m4), bb[0])))); \
        float g1 = fmaf(cw[1], (t1), fmaf(cdw[1], (t2), fmaf(cu[1], (m3), fmaf(cdu[1], (m4), bb[1])))); \
        float g2 = fmaf(cw[2], (t1), fmaf(cdw[2], (t2), fmaf(cu[2], (m3), fmaf(cdu[2], (m4), bb[2])))); \
        float g3 = fmaf(cw[3], (t1), fmaf(cdw[3], (t2), fmaf(cu[3], (m3), fmaf(cdu[3], (m4), bb[3])))); \
        float ig = rcp_fast(1.0f + exp2_fast(g0));                            \
        float fg = rcp_fast(1.0f + exp2_fast(g1));                            \
        float gg = fmaf(-2.0f, rcp_fast(1.0f + exp2_fast(g2)), 1.0f);         \
        float og = rcp_fast(1.0f + exp2_fast(g3));                            \
        cS = fmaf(fg, cS, ig * gg);                                           \
        hS = og * fmaf(-2.0f, rcp_fast(1.0f + exp2_fast(cS * (2.0f * L2E))), 1.0f); \
    }

// ---------------------------------------------------------------------------
// Kernel A: PT[bt][g] = float4{(W12@x)[g], (W12@x)[g+4], (dW12@x)[g],
// (dW12@x)[g+4]} for g = 0..3 (producer wave-g layout)
// ---------------------------------------------------------------------------
__global__ __launch_bounds__(64) void precomp_kernel(
    const float* __restrict__ x, const float* __restrict__ W12,
    const float* __restrict__ dW12, float* __restrict__ PT) {
    int bt = blockIdx.x;
    int l = threadIdx.x;
    const float4* xr = (const float4*)(x + (size_t)bt * ND);
    float4 xv0 = xr[l];
    float4 xv1 = xr[64 + l];

    float acc[16];
#pragma unroll
    for (int f = 0; f < 8; ++f) {
        const float4* w = (const float4*)(W12 + f * ND);
        float4 a = w[l], b = w[64 + l];
        float s = a.x * xv0.x;
        s = fmaf(a.y, xv0.y, s); s = fmaf(a.z, xv0.z, s); s = fmaf(a.w, xv0.w, s);
        s = fmaf(b.x, xv1.x, s); s = fmaf(b.y, xv1.y, s); s = fmaf(b.z, xv1.z, s);
        s = fmaf(b.w, xv1.w, s);
        acc[f] = s;
        const float4* dw = (const float4*)(dW12 + f * ND);
        float4 c = dw[l], d = dw[64 + l];
        float u = c.x * xv0.x;
        u = fmaf(c.y, xv0.y, u); u = fmaf(c.z, xv0.z, u); u = fmaf(c.w, xv0.w, u);
        u = fmaf(d.x, xv1.x, u); u = fmaf(d.y, xv1.y, u); u = fmaf(d.z, xv1.z, u);
        u = fmaf(d.w, xv1.w, u);
        acc[8 + f] = u;
    }
#pragma unroll
    for (int f = 0; f < 16; ++f) acc[f] = dpp_sum64(acc[f]);

    if (l == 63) {
        float4* o = (float4*)(PT + (size_t)bt * 16);
#pragma unroll
        for (int g = 0; g < 4; ++g)
            o[g] = make_float4(acc[g], acc[g + 4], acc[8 + g], acc[12 + g]);
    }
}

// ---------------------------------------------------------------------------
// Kernel B: FUSED producer+consumer, one 8-wave block per batch element.
// Waves 0-3 (producer, factor pair {g,g+4}): layer-1 recurrence at step i;
//   W22 projections of h1(i) computed AFTER the gates (off the critical
//   chain) -> mr[(i-1)&1].
// Waves 4-7 (consumer): layer-2 recurrence at s=i-2; computes its dW22
//   projections ITSELF from the h1 ring (free intra-block handoff).
// h1 lives in a 4-slot LDS ring: producer writes slot (i+1)&3, reads i&3,
// consumer reads (i-1)&3 — pairwise distinct mod 4, race-free.
// ONE lgkm-only barrier per iteration; balanced 6 dots/wave on both sides.
// ---------------------------------------------------------------------------
__global__ __launch_bounds__(512, 2) void lstm_fused_kernel(
    const float* __restrict__ PT, const float* __restrict__ h0,
    const float* __restrict__ c0,
    const float* __restrict__ W11, const float* __restrict__ U11,
    const float* __restrict__ dW11, const float* __restrict__ dU11,
    const float* __restrict__ U12, const float* __restrict__ dU12,
    const float* __restrict__ b11, const float* __restrict__ b12,
    const float* __restrict__ W21, const float* __restrict__ U21,
    const float* __restrict__ dW21, const float* __restrict__ dU21,
    const float* __restrict__ W22, const float* __restrict__ dW22,
    const float* __restrict__ U22, const float* __restrict__ dU22,
    const float* __restrict__ b21, const float* __restrict__ b22,
    float* __restrict__ out) {
    int b = blockIdx.x;
    int tid = threadIdx.x;
    int wv = tid >> 6;
    int l = tid & 63;
    int g = wv & 3;                 // factor pair {g, g+4}
    int kb = 32 * (l & 15) + (l >> 4);
    int rA = 8 * l + g, rB = 8 * l + g + 4;   // owned rows

    __shared__ float Ps[NS * 16];   // 32 KB staged P slice
    __shared__ float hb1[4][NH];    // layer-1 h ring (permuted slots)
    __shared__ float hb2[2][NH];    // layer-2 h double buffer
    __shared__ float mr[2][8];      // W22-projection handoff

    // stage P (all 8 waves)
    {
        const float4* src = (const float4*)(PT + (size_t)b * NS * 16);
        float4* dst = (float4*)Ps;
#pragma unroll
        for (int i = 0; i < 4; ++i) dst[tid + i * 512] = src[tid + i * 512];
    }

    float* hn = out + (size_t)NB * NS * NH;
    float* cn = hn + (size_t)2 * NB * NH;
    const float SQ[4] = {-L2E, -L2E, 2.0f * L2E, -L2E};

    if (wv < 4) {
        // ========================= PRODUCER (layer 1) ======================
        float wU0[8], wU1[8], wD0[8], wD1[8], wW0[8], wW1[8];
        LW(U12, g, wU0)      LW(U12, g + 4, wU1)
        LW(dU12, g, wD0)     LW(dU12, g + 4, wD1)
        LW(W22, g, wW0)      LW(W22, g + 4, wW1)

        float cw[4], cdw[4], cu[4], cdu[4], bbA[4], bbB[4];
#pragma unroll
        for (int q = 0; q < 4; ++q) {
            cw[q] = W11[q * 64 + l] * SQ[q];
            cdw[q] = dW11[q * 64 + l] * SQ[q];
            cu[q] = U11[q * 64 + l] * SQ[q];
            cdu[q] = dU11[q * 64 + l] * SQ[q];
            bbA[q] = (b11[q * NH + rA] + b12[q * NH + rA]) * SQ[q];
            bbB[q] = (b11[q * NH + rB] + b12[q * NH + rB]) * SQ[q];
        }
        float hA = h0[(size_t)b * NH + rA], hB = h0[(size_t)b * NH + rB];
        float cA = c0[(size_t)b * NH + rA], cB = c0[(size_t)b * NH + rB];
        hb1[0][64 * g + l] = hA;
        hb1[0][64 * (g + 4) + l] = hB;
        wg_barrier();

        for (int i = 0; i <= NS + 1; ++i) {
            if (i <= NS) {
                float4 x0 = *(const float4*)&hb1[i & 3][4 * l];
                float4 x1 = *(const float4*)&hb1[i & 3][256 + 4 * l];
                if (i < NS) {
                    // critical chain: U dots -> gates -> h write
                    float rUa = dpp_sum64(dot8s(wU0, x0, x1));
                    float rUb = dpp_sum64(dot8s(wU1, x0, x1));
                    float rDa = dpp_sum64(dot8s(wD0, x0, x1));
                    float rDb = dpp_sum64(dot8s(wD1, x0, x1));
                    float m3A = bcast63(rUa), m3B = bcast63(rUb);
                    float m4A = bcast63(rDa), m4B = bcast63(rDb);
                    float4 pv = *(const float4*)&Ps[i * 16 + 4 * g];
                    GATEX(pv.x, pv.z, m3A, m4A, bbA, cA, hA)
                    GATEX(pv.y, pv.w, m3B, m4B, bbB, cB, hB)
                    hb1[(i + 1) & 3][64 * g + l] = hA;
                    hb1[(i + 1) & 3][64 * (g + 4) + l] = hB;
                }
                // off-chain: W22 projections of h1(i) (regs still live)
                float rWa = dpp_sum64(dot8s(wW0, x0, x1));
                float rWb = dpp_sum64(dot8s(wW1, x0, x1));
                if (i > 0 && l == 63)
                    *(float2*)&mr[(i - 1) & 1][2 * g] = make_float2(rWa, rWb);
            }
            wg_barrier();
        }
        hn[(size_t)b * NH + rA] = hA;
        hn[(size_t)b * NH + rB] = hB;
        cn[(size_t)b * NH + rA] = cA;
        cn[(size_t)b * NH + rB] = cB;
    } else {
        // ========================= CONSUMER (layer 2) ======================
        float wU0[8], wU1[8], wD0[8], wD1[8], wV0[8], wV1[8];
        LW(U22, g, wU0)      LW(U22, g + 4, wU1)
        LW(dU22, g, wD0)     LW(dU22, g + 4, wD1)
        LW(dW22, g, wV0)     LW(dW22, g + 4, wV1)

        float cw[4], cdw[4], cu[4], cdu[4], bbA[4], bbB[4];
#pragma unroll
        for (int q = 0; q < 4; ++q) {
            cw[q] = W21[q * 64 + l] * SQ[q];
            cdw[q] = dW21[q * 64 + l] * SQ[q];
            cu[q] = U21[q * 64 + l] * SQ[q];
            cdu[q] = dU21[q * 64 + l] * SQ[q];
            bbA[q] = (b21[q * NH + rA] + b22[q * NH + rA]) * SQ[q];
            bbB[q] = (b21[q * NH + rB] + b22[q * NH + rB]) * SQ[q];
        }
        const float* h0p = h0 + (size_t)NB * NH + (size_t)b * NH;
        const float* c0p = c0 + (size_t)NB * NH + (size_t)b * NH;
        float hA = h0p[rA], hB = h0p[rB];
        float cA = c0p[rA], cB = c0p[rB];
        hb2[0][64 * g + l] = hA;
        hb2[0][64 * (g + 4) + l] = hB;
        wg_barrier();

        float* outb = out + (size_t)b * NS * NH;
        for (int i = 0; i <= NS + 1; ++i) {
            int s = i - 2;
            if (s >= 0) {
                // issue all reads up front (wave-uniform mr first)
                float2 mv = *(const float2*)&mr[s & 1][2 * g];
                float4 y0 = *(const float4*)&hb2[s & 1][4 * l];
                float4 y1 = *(const float4*)&hb2[s & 1][256 + 4 * l];
                float4 x0 = *(const float4*)&hb1[(s + 1) & 3][4 * l];
                float4 x1 = *(const float4*)&hb1[(s + 1) & 3][256 + 4 * l];
                // 6 interleaved dots
                float rUa = dpp_sum64(dot8s(wU0, y0, y1));
                float rUb = dpp_sum64(dot8s(wU1, y0, y1));
                float rDa = dpp_sum64(dot8s(wD0, y0, y1));
                float rDb = dpp_sum64(dot8s(wD1, y0, y1));
                float rVa = dpp_sum64(dot8s(wV0, x0, x1));
                float rVb = dpp_sum64(dot8s(wV1, x0, x1));
                float m5A = bcast63(rUa), m5B = bcast63(rUb);
                float m6A = bcast63(rDa), m6B = bcast63(rDb);
                float m2A = bcast63(rVa), m2B = bcast63(rVb);
                GATEX(mv.x, m2A, m5A, m6A, bbA, cA, hA)
                GATEX(mv.y, m2B, m5B, m6B, bbB, cB, hB)
                hb2[(s + 1) & 1][64 * g + l] = hA;
                hb2[(s + 1) & 1][64 * (g + 4) + l] = hB;
                outb[(size_t)s * NH + rA] = hA;   // fire-and-forget
                outb[(size_t)s * NH + rB] = hB;
            }
            wg_barrier();
        }
        hn[(size_t)NB * NH + (size_t)b * NH + rA] = hA;
        hn[(size_t)NB * NH + (size_t)b * NH + rB] = hB;
        cn[(size_t)NB * NH + (size_t)b * NH + rA] = cA;
        cn[(size_t)NB * NH + (size_t)b * NH + rB] = cB;
    }
}

extern "C" void kernel_launch(void* const* d_in, const int* in_sizes, int n_in,
                              void* d_out, int out_size, void* d_ws, size_t ws_size,
                              hipStream_t stream) {
    const float* x = (const float*)d_in[0];
    const float* h0 = (const float*)d_in[1];
    const float* c0 = (const float*)d_in[2];
    const float* W11 = (const float*)d_in[3];
    const float* W12 = (const float*)d_in[4];
    const float* U11 = (const float*)d_in[5];
    const float* U12 = (const float*)d_in[6];
    const float* dW11 = (const float*)d_in[7];
    const float* dW12 = (const float*)d_in[8];
    const float* dU11 = (const float*)d_in[9];
    const float* dU12 = (const float*)d_in[10];
    const float* b11 = (const float*)d_in[11];
    const float* b12 = (const float*)d_in[12];
    const float* W21 = (const float*)d_in[13];
    const float* W22 = (const float*)d_in[14];
    const float* U21 = (const float*)d_in[15];
    const float* U22 = (const float*)d_in[16];
    const float* dW21 = (const float*)d_in[17];
    const float* dW22 = (const float*)d_in[18];
    const float* dU21 = (const float*)d_in[19];
    const float* dU22 = (const float*)d_in[20];
    const float* b21 = (const float*)d_in[21];
    const float* b22 = (const float*)d_in[22];

    float* PT = (float*)d_ws;   // 2 MB
    float* out = (float*)d_out;

    hipLaunchKernelGGL(precomp_kernel, dim3(NB * NS), dim3(64), 0, stream,
                       x, W12, dW12, PT);
    hipLaunchKernelGGL(lstm_fused_kernel, dim3(NB), dim3(512), 0, stream,
                       PT, h0, c0,
                       W11, U11, dW11, dU11, U12, dU12, b11, b12,
                       W21, U21, dW21, dU21, W22, dW22, U22, dU22, b21, b22,
                       out);
}

// Round 16
// 438.846 us; speedup vs baseline: 1.0942x; 1.0081x over previous
//
#include <hip/hip_runtime.h>
#include <math.h>

#define NB 64       // batch
#define NS 512      // seq len
#define ND 512      // input dim
#define NH 512      // hidden
#define L2E 1.4426950408889634f

typedef float v2f __attribute__((ext_vector_type(2)));

// CDNA4 packed dual-fp32 FMA (VOP3P): 2 fp32 FMAs per instruction
__device__ __forceinline__ v2f pk_fma(v2f a, v2f b, v2f c) {
    v2f d;
    asm("v_pk_fma_f32 %0, %1, %2, %3" : "=v"(d) : "v"(a), "v"(b), "v"(c));
    return d;
}
__device__ __forceinline__ v2f pk_mul(v2f a, v2f b) {
    v2f d;
    asm("v_pk_mul_f32 %0, %1, %2" : "=v"(d) : "v"(a), "v"(b));
    return d;
}

// 64-lane sum via DPP (VALU only). Total lands in lane 63.
__device__ __forceinline__ float dpp_sum64(float x) {
    x += __int_as_float(__builtin_amdgcn_update_dpp(0, __float_as_int(x), 0x111, 0xf, 0xf, true)); // row_shr:1
    x += __int_as_float(__builtin_amdgcn_update_dpp(0, __float_as_int(x), 0x112, 0xf, 0xf, true)); // row_shr:2
    x += __int_as_float(__builtin_amdgcn_update_dpp(0, __float_as_int(x), 0x114, 0xf, 0xf, true)); // row_shr:4
    x += __int_as_float(__builtin_amdgcn_update_dpp(0, __float_as_int(x), 0x118, 0xf, 0xf, true)); // row_shr:8
    x += __int_as_float(__builtin_amdgcn_update_dpp(0, __float_as_int(x), 0x142, 0xa, 0xf, true)); // row_bcast:15
    x += __int_as_float(__builtin_amdgcn_update_dpp(0, __float_as_int(x), 0x143, 0xc, 0xf, true)); // row_bcast:31
    return x;
}

__device__ __forceinline__ float bcast63(float x) {
    return __int_as_float(__builtin_amdgcn_readlane(__float_as_int(x), 63));
}
__device__ __forceinline__ float rcp_fast(float x) { return __builtin_amdgcn_rcpf(x); }
__device__ __forceinline__ float exp2_fast(float x) {
    float r;
    asm("v_exp_f32 %0, %1" : "=v"(r) : "v"(x));
    return r;
}
__device__ __forceinline__ void wg_barrier() {
    asm volatile("s_waitcnt lgkmcnt(0)\n\ts_barrier" ::: "memory");
}

// packed dot of an 8-elem weight (4 v2f pairs) against the h float4 pair
__device__ __forceinline__ float dot8pk(const v2f* w, v2f x01, v2f x23,
                                        v2f x45, v2f x67) {
    v2f a = pk_mul(w[0], x01);
    a = pk_fma(w[1], x23, a);
    a = pk_fma(w[2], x45, a);
    a = pk_fma(w[3], x67, a);
    return a.x + a.y;
}

// permuted gather of factor row f into v2f pairs matching x-pairing
#define LWPK(mat, f, wp)                                                      \
    {                                                                         \
        const float* M = (mat) + (f) * NH;                                    \
        wp[0] = (v2f){M[kb], M[kb + 8]};                                      \
        wp[1] = (v2f){M[kb + 16], M[kb + 24]};                                \
        wp[2] = (v2f){M[kb + 4], M[kb + 12]};                                 \
        wp[3] = (v2f){M[kb + 20], M[kb + 28]};                                \
    }

// one LSTM row update; coefficients pre-scaled by {-L2E,-L2E,+2L2E,-L2E}:
//   sigm -> 1/(1+2^g), tanh -> 1-2/(1+2^g)
#define GATEX(t1, t2, m3, m4, bb, cS, hS)                                     \
    {                                                                         \
        float g0 = fmaf(cw[0], (t1), fmaf(cdw[0], (t2), fmaf(cu[0], (m3), fmaf(cdu[0], (m4), bb[0])))); \
        float g1 = fmaf(cw[1], (t1), fmaf(cdw[1], (t2), fmaf(cu[1], (m3), fmaf(cdu[1], (m4), bb[1])))); \
        float g2 = fmaf(cw[2], (t1), fmaf(cdw[2], (t2), fmaf(cu[2], (m3), fmaf(cdu[2], (m4), bb[2])))); \
        float g3 = fmaf(cw[3], (t1), fmaf(cdw[3], (t2), fmaf(cu[3], (m3), fmaf(cdu[3], (m4), bb[3])))); \
        float ig = rcp_fast(1.0f + exp2_fast(g0));                            \
        float fg = rcp_fast(1.0f + exp2_fast(g1));                            \
        float gg = fmaf(-2.0f, rcp_fast(1.0f + exp2_fast(g2)), 1.0f);         \
        float og = rcp_fast(1.0f + exp2_fast(g3));                            \
        cS = fmaf(fg, cS, ig * gg);                                           \
        hS = og * fmaf(-2.0f, rcp_fast(1.0f + exp2_fast(cS * (2.0f * L2E))), 1.0f); \
    }

// ---------------------------------------------------------------------------
// Kernel A: PT[bt][g] = float4{(W12@x)[g], (W12@x)[g+4], (dW12@x)[g],
// (dW12@x)[g+4]} for g = 0..3 (producer wave-g layout)
// ---------------------------------------------------------------------------
__global__ __launch_bounds__(64) void precomp_kernel(
    const float* __restrict__ x, const float* __restrict__ W12,
    const float* __restrict__ dW12, float* __restrict__ PT) {
    int bt = blockIdx.x;
    int l = threadIdx.x;
    const float4* xr = (const float4*)(x + (size_t)bt * ND);
    float4 xv0 = xr[l];
    float4 xv1 = xr[64 + l];
    v2f x01 = {xv0.x, xv0.y}, x23 = {xv0.z, xv0.w};
    v2f x45 = {xv1.x, xv1.y}, x67 = {xv1.z, xv1.w};

    float acc[16];
#pragma unroll
    for (int f = 0; f < 8; ++f) {
        const float4* w = (const float4*)(W12 + f * ND);
        float4 a = w[l], b = w[64 + l];
        v2f wp[4] = {{a.x, a.y}, {a.z, a.w}, {b.x, b.y}, {b.z, b.w}};
        acc[f] = dot8pk(wp, x01, x23, x45, x67);
        const float4* dw = (const float4*)(dW12 + f * ND);
        float4 c = dw[l], d = dw[64 + l];
        v2f vp[4] = {{c.x, c.y}, {c.z, c.w}, {d.x, d.y}, {d.z, d.w}};
        acc[8 + f] = dot8pk(vp, x01, x23, x45, x67);
    }
#pragma unroll
    for (int f = 0; f < 16; ++f) acc[f] = dpp_sum64(acc[f]);

    if (l == 63) {
        float4* o = (float4*)(PT + (size_t)bt * 16);
#pragma unroll
        for (int g = 0; g < 4; ++g)
            o[g] = make_float4(acc[g], acc[g + 4], acc[8 + g], acc[12 + g]);
    }
}

// ---------------------------------------------------------------------------
// Kernel B: FUSED producer+consumer (R12 structure), one 8-wave block per
// batch element. Waves 0-3 (producer, factors {g,g+4}): layer-1 recurrence
// + W22/dW22 projections -> mr[(i-1)&1]. Waves 4-7 (consumer): layer-2 at
// s = i-2. Packed pk_fma dots; branch-free main loop (peeled pro/epilogue);
// ONE lgkm-only barrier per iteration; fire-and-forget out stores.
// ---------------------------------------------------------------------------
__global__ __launch_bounds__(512, 2) void lstm_fused_kernel(
    const float* __restrict__ PT, const float* __restrict__ h0,
    const float* __restrict__ c0,
    const float* __restrict__ W11, const float* __restrict__ U11,
    const float* __restrict__ dW11, const float* __restrict__ dU11,
    const float* __restrict__ U12, const float* __restrict__ dU12,
    const float* __restrict__ b11, const float* __restrict__ b12,
    const float* __restrict__ W21, const float* __restrict__ U21,
    const float* __restrict__ dW21, const float* __restrict__ dU21,
    const float* __restrict__ W22, const float* __restrict__ dW22,
    const float* __restrict__ U22, const float* __restrict__ dU22,
    const float* __restrict__ b21, const float* __restrict__ b22,
    float* __restrict__ out) {
    int b = blockIdx.x;
    int tid = threadIdx.x;
    int wv = tid >> 6;
    int l = tid & 63;
    int g = wv & 3;                 // factor pair {g, g+4}
    int kb = 32 * (l & 15) + (l >> 4);
    int rA = 8 * l + g, rB = 8 * l + g + 4;   // owned rows

    __shared__ float Ps[NS * 16];   // 32 KB staged P slice
    __shared__ float hb1[2][NH];    // layer-1 h (permuted slots)
    __shared__ float hb2[2][NH];    // layer-2 h
    __shared__ float mr[2][16];     // L1->L2 projection handoff

    // stage P (all 8 waves)
    {
        const float4* src = (const float4*)(PT + (size_t)b * NS * 16);
        float4* dst = (float4*)Ps;
#pragma unroll
        for (int i = 0; i < 4; ++i) dst[tid + i * 512] = src[tid + i * 512];
    }

    float* hn = out + (size_t)NB * NS * NH;
    float* cn = hn + (size_t)2 * NB * NH;
    const float SQ[4] = {-L2E, -L2E, 2.0f * L2E, -L2E};

    if (wv < 4) {
        // ========================= PRODUCER (layer 1) ======================
        v2f wU0[4], wU1[4], wD0[4], wD1[4], wW0[4], wW1[4], wV0[4], wV1[4];
        LWPK(U12, g, wU0)      LWPK(U12, g + 4, wU1)
        LWPK(dU12, g, wD0)     LWPK(dU12, g + 4, wD1)
        LWPK(W22, g, wW0)      LWPK(W22, g + 4, wW1)
        LWPK(dW22, g, wV0)     LWPK(dW22, g + 4, wV1)

        float cw[4], cdw[4], cu[4], cdu[4], bbA[4], bbB[4];
#pragma unroll
        for (int q = 0; q < 4; ++q) {
            cw[q] = W11[q * 64 + l] * SQ[q];
            cdw[q] = dW11[q * 64 + l] * SQ[q];
            cu[q] = U11[q * 64 + l] * SQ[q];
            cdu[q] = dU11[q * 64 + l] * SQ[q];
            bbA[q] = (b11[q * NH + rA] + b12[q * NH + rA]) * SQ[q];
            bbB[q] = (b11[q * NH + rB] + b12[q * NH + rB]) * SQ[q];
        }
        float hA = h0[(size_t)b * NH + rA], hB = h0[(size_t)b * NH + rB];
        float cA = c0[(size_t)b * NH + rA], cB = c0[(size_t)b * NH + rB];
        hb1[0][64 * g + l] = hA;
        hb1[0][64 * (g + 4) + l] = hB;
        wg_barrier();

        auto prod_full = [&](int i, bool domr) {
            float4 x0 = *(const float4*)&hb1[i & 1][4 * l];
            float4 x1 = *(const float4*)&hb1[i & 1][256 + 4 * l];
            v2f x01 = {x0.x, x0.y}, x23 = {x0.z, x0.w};
            v2f x45 = {x1.x, x1.y}, x67 = {x1.z, x1.w};
            float rWa = dpp_sum64(dot8pk(wW0, x01, x23, x45, x67));
            float rWb = dpp_sum64(dot8pk(wW1, x01, x23, x45, x67));
            if (domr && l == 63)
                *(float2*)&mr[(i - 1) & 1][2 * g] = make_float2(rWa, rWb);
            float rVa = dpp_sum64(dot8pk(wV0, x01, x23, x45, x67));
            float rVb = dpp_sum64(dot8pk(wV1, x01, x23, x45, x67));
            if (domr && l == 63)
                *(float2*)&mr[(i - 1) & 1][8 + 2 * g] = make_float2(rVa, rVb);
            float rUa = dpp_sum64(dot8pk(wU0, x01, x23, x45, x67));
            float rUb = dpp_sum64(dot8pk(wU1, x01, x23, x45, x67));
            float rDa = dpp_sum64(dot8pk(wD0, x01, x23, x45, x67));
            float rDb = dpp_sum64(dot8pk(wD1, x01, x23, x45, x67));
            float m3A = bcast63(rUa), m3B = bcast63(rUb);
            float m4A = bcast63(rDa), m4B = bcast63(rDb);
            float4 pv = *(const float4*)&Ps[i * 16 + 4 * g];
            GATEX(pv.x, pv.z, m3A, m4A, bbA, cA, hA)
            GATEX(pv.y, pv.w, m3B, m4B, bbB, cB, hB)
            hb1[(i + 1) & 1][64 * g + l] = hA;
            hb1[(i + 1) & 1][64 * (g + 4) + l] = hB;
        };

        // prologue: i = 0 (no mr), i = 1
        prod_full(0, false);
        wg_barrier();
        prod_full(1, true);
        wg_barrier();
        // main loop: branch-free
        for (int i = 2; i < NS; ++i) {
            prod_full(i, true);
            wg_barrier();
        }
        // epilogue i = NS: only projections of h1(NS) -> mr for s = NS-1
        {
            float4 x0 = *(const float4*)&hb1[NS & 1][4 * l];
            float4 x1 = *(const float4*)&hb1[NS & 1][256 + 4 * l];
            v2f x01 = {x0.x, x0.y}, x23 = {x0.z, x0.w};
            v2f x45 = {x1.x, x1.y}, x67 = {x1.z, x1.w};
            float rWa = dpp_sum64(dot8pk(wW0, x01, x23, x45, x67));
            float rWb = dpp_sum64(dot8pk(wW1, x01, x23, x45, x67));
            float rVa = dpp_sum64(dot8pk(wV0, x01, x23, x45, x67));
            float rVb = dpp_sum64(dot8pk(wV1, x01, x23, x45, x67));
            if (l == 63) {
                *(float2*)&mr[(NS - 1) & 1][2 * g] = make_float2(rWa, rWb);
                *(float2*)&mr[(NS - 1) & 1][8 + 2 * g] = make_float2(rVa, rVb);
            }
        }
        wg_barrier();
        wg_barrier();  // match consumer's final iteration
        hn[(size_t)b * NH + rA] = hA;
        hn[(size_t)b * NH + rB] = hB;
        cn[(size_t)b * NH + rA] = cA;
        cn[(size_t)b * NH + rB] = cB;
    } else {
        // ========================= CONSUMER (layer 2) ======================
        v2f wU0[4], wU1[4], wD0[4], wD1[4];
        LWPK(U22, g, wU0)      LWPK(U22, g + 4, wU1)
        LWPK(dU22, g, wD0)     LWPK(dU22, g + 4, wD1)

        float cw[4], cdw[4], cu[4], cdu[4], bbA[4], bbB[4];
#pragma unroll
        for (int q = 0; q < 4; ++q) {
            cw[q] = W21[q * 64 + l] * SQ[q];
            cdw[q] = dW21[q * 64 + l] * SQ[q];
            cu[q] = U21[q * 64 + l] * SQ[q];
            cdu[q] = dU21[q * 64 + l] * SQ[q];
            bbA[q] = (b21[q * NH + rA] + b22[q * NH + rA]) * SQ[q];
            bbB[q] = (b21[q * NH + rB] + b22[q * NH + rB]) * SQ[q];
        }
        const float* h0p = h0 + (size_t)NB * NH + (size_t)b * NH;
        const float* c0p = c0 + (size_t)NB * NH + (size_t)b * NH;
        float hA = h0p[rA], hB = h0p[rB];
        float cA = c0p[rA], cB = c0p[rB];
        hb2[0][64 * g + l] = hA;
        hb2[0][64 * (g + 4) + l] = hB;
        wg_barrier();

        float* outb = out + (size_t)b * NS * NH;
        auto cons_step = [&](int s) {
            float4 mv = *(const float4*)&mr[s & 1][4 * g];  // {W g, W g+4, ...}
            float2 mw = *(const float2*)&mr[s & 1][2 * g];
            float2 mv2 = *(const float2*)&mr[s & 1][8 + 2 * g];
            float4 y0 = *(const float4*)&hb2[s & 1][4 * l];
            float4 y1 = *(const float4*)&hb2[s & 1][256 + 4 * l];
            v2f y01 = {y0.x, y0.y}, y23 = {y0.z, y0.w};
            v2f y45 = {y1.x, y1.y}, y67 = {y1.z, y1.w};
            float rUa = dpp_sum64(dot8pk(wU0, y01, y23, y45, y67));
            float rUb = dpp_sum64(dot8pk(wU1, y01, y23, y45, y67));
            float rDa = dpp_sum64(dot8pk(wD0, y01, y23, y45, y67));
            float rDb = dpp_sum64(dot8pk(wD1, y01, y23, y45, y67));
            float m5A = bcast63(rUa), m5B = bcast63(rUb);
            float m6A = bcast63(rDa), m6B = bcast63(rDb);
            GATEX(mw.x, mv2.x, m5A, m6A, bbA, cA, hA)
            GATEX(mw.y, mv2.y, m5B, m6B, bbB, cB, hB)
            hb2[(s + 1) & 1][64 * g + l] = hA;
            hb2[(s + 1) & 1][64 * (g + 4) + l] = hB;
            outb[(size_t)s * NH + rA] = hA;   // fire-and-forget
            outb[(size_t)s * NH + rB] = hB;
            (void)mv;
        };

        // prologue: producer's i = 0, 1 slots (idle)
        wg_barrier();
        wg_barrier();
        // main loop: s = i-2 for i in [2, NS)
        for (int i = 2; i < NS; ++i) {
            cons_step(i - 2);
            wg_barrier();
        }
        // epilogue: s = NS-2 (producer computes final mr in this slot)
        cons_step(NS - 2);
        wg_barrier();
        cons_step(NS - 1);
        wg_barrier();
        hn[(size_t)NB * NH + (size_t)b * NH + rA] = hA;
        hn[(size_t)NB * NH + (size_t)b * NH + rB] = hB;
        cn[(size_t)NB * NH + (size_t)b * NH + rA] = cA;
        cn[(size_t)NB * NH + (size_t)b * NH + rB] = cB;
    }
}

extern "C" void kernel_launch(void* const* d_in, const int* in_sizes, int n_in,
                              void* d_out, int out_size, void* d_ws, size_t ws_size,
                              hipStream_t stream) {
    const float* x = (const float*)d_in[0];
    const float* h0 = (const float*)d_in[1];
    const float* c0 = (const float*)d_in[2];
    const float* W11 = (const float*)d_in[3];
    const float* W12 = (const float*)d_in[4];
    const float* U11 = (const float*)d_in[5];
    const float* U12 = (const float*)d_in[6];
    const float* dW11 = (const float*)d_in[7];
    const float* dW12 = (const float*)d_in[8];
    const float* dU11 = (const float*)d_in[9];
    const float* dU12 = (const float*)d_in[10];
    const float* b11 = (const float*)d_in[11];
    const float* b12 = (const float*)d_in[12];
    const float* W21 = (const float*)d_in[13];
    const float* W22 = (const float*)d_in[14];
    const float* U21 = (const float*)d_in[15];
    const float* U22 = (const float*)d_in[16];
    const float* dW21 = (const float*)d_in[17];
    const float* dW22 = (const float*)d_in[18];
    const float* dU21 = (const float*)d_in[19];
    const float* dU22 = (const float*)d_in[20];
    const float* b21 = (const float*)d_in[21];
    const float* b22 = (const float*)d_in[22];

    float* PT = (float*)d_ws;   // 2 MB
    float* out = (float*)d_out;

    hipLaunchKernelGGL(precomp_kernel, dim3(NB * NS), dim3(64), 0, stream,
                       x, W12, dW12, PT);
    hipLaunchKernelGGL(lstm_fused_kernel, dim3(NB), dim3(512), 0, stream,
                       PT, h0, c0,
                       W11, U11, dW11, dU11, U12, dU12, b11, b12,
                       W21, U21, dW21, dU21, W22, dW22, U22, dU22, b21, b22,
                       out);
}

// Round 17
// 424.869 us; speedup vs baseline: 1.1302x; 1.0329x over previous
//
#include <hip/hip_runtime.h>
#include <math.h>

#define NB 64       // batch
#define NS 512      // seq len
#define ND 512      // input dim
#define NH 512      // hidden
#define L2E 1.4426950408889634f

// 64-lane sum via DPP (VALU only). Total lands in lane 63.
__device__ __forceinline__ float dpp_sum64(float x) {
    x += __int_as_float(__builtin_amdgcn_update_dpp(0, __float_as_int(x), 0x111, 0xf, 0xf, true)); // row_shr:1
    x += __int_as_float(__builtin_amdgcn_update_dpp(0, __float_as_int(x), 0x112, 0xf, 0xf, true)); // row_shr:2
    x += __int_as_float(__builtin_amdgcn_update_dpp(0, __float_as_int(x), 0x114, 0xf, 0xf, true)); // row_shr:4
    x += __int_as_float(__builtin_amdgcn_update_dpp(0, __float_as_int(x), 0x118, 0xf, 0xf, true)); // row_shr:8
    x += __int_as_float(__builtin_amdgcn_update_dpp(0, __float_as_int(x), 0x142, 0xa, 0xf, true)); // row_bcast:15
    x += __int_as_float(__builtin_amdgcn_update_dpp(0, __float_as_int(x), 0x143, 0xc, 0xf, true)); // row_bcast:31
    return x;
}

__device__ __forceinline__ float bcast63(float x) {
    return __int_as_float(__builtin_amdgcn_readlane(__float_as_int(x), 63));
}
__device__ __forceinline__ float rcp_fast(float x) { return __builtin_amdgcn_rcpf(x); }
__device__ __forceinline__ float exp2_fast(float x) {
    float r;
    asm("v_exp_f32 %0, %1" : "=v"(r) : "v"(x));
    return r;
}
__device__ __forceinline__ void wg_barrier() {
    asm volatile("s_waitcnt lgkmcnt(0)\n\ts_barrier" ::: "memory");
}

// dot of an 8-float weight slice against the two h float4s
__device__ __forceinline__ float dot8s(const float* s, float4 x0, float4 x1) {
    float r = s[0] * x0.x;
    r = fmaf(s[1], x0.y, r); r = fmaf(s[2], x0.z, r); r = fmaf(s[3], x0.w, r);
    r = fmaf(s[4], x1.x, r); r = fmaf(s[5], x1.y, r); r = fmaf(s[6], x1.z, r);
    r = fmaf(s[7], x1.w, r);
    return r;
}

// permuted gather of factor row f (LDS slot s holds row 8*(s&63)+(s>>6))
#define LW(mat, f, arr)                                                       \
    {                                                                         \
        const float* M = (mat) + (f) * NH;                                    \
        arr[0] = M[kb];      arr[1] = M[kb + 8];                              \
        arr[2] = M[kb + 16]; arr[3] = M[kb + 24];                             \
        arr[4] = M[kb + 4];  arr[5] = M[kb + 12];                             \
        arr[6] = M[kb + 20]; arr[7] = M[kb + 28];                             \
    }

// one LSTM row update; coefficients pre-scaled by {-L2E,-L2E,+2L2E,-L2E}:
//   sigm -> 1/(1+2^g), tanh -> 1-2/(1+2^g)
#define GATEX(t1, t2, m3, m4, bb, cS, hS)                                     \
    {                                                                         \
        float g0 = fmaf(cw[0], (t1), fmaf(cdw[0], (t2), fmaf(cu[0], (m3), fmaf(cdu[0], (m4), bb[0])))); \
        float g1 = fmaf(cw[1], (t1), fmaf(cdw[1], (t2), fmaf(cu[1], (m3), fmaf(cdu[1], (m4), bb[1])))); \
        float g2 = fmaf(cw[2], (t1), fmaf(cdw[2], (t2), fmaf(cu[2], (m3), fmaf(cdu[2], (m4), bb[2])))); \
        float g3 = fmaf(cw[3], (t1), fmaf(cdw[3], (t2), fmaf(cu[3], (m3), fmaf(cdu[3], (m4), bb[3])))); \
        float ig = rcp_fast(1.0f + exp2_fast(g0));                            \
        float fg = rcp_fast(1.0f + exp2_fast(g1));                            \
        float gg = fmaf(-2.0f, rcp_fast(1.0f + exp2_fast(g2)), 1.0f);         \
        float og = rcp_fast(1.0f + exp2_fast(g3));                            \
        cS = fmaf(fg, cS, ig * gg);                                           \
        hS = og * fmaf(-2.0f, rcp_fast(1.0f + exp2_fast(cS * (2.0f * L2E))), 1.0f); \
    }

// ---------------------------------------------------------------------------
// Kernel A: PT[bt] as 8 x float2: {(W12@x)[g], (dW12@x)[g]} for g = 0..7
// ---------------------------------------------------------------------------
__global__ __launch_bounds__(64) void precomp_kernel(
    const float* __restrict__ x, const float* __restrict__ W12,
    const float* __restrict__ dW12, float* __restrict__ PT) {
    int bt = blockIdx.x;
    int l = threadIdx.x;
    const float4* xr = (const float4*)(x + (size_t)bt * ND);
    float4 xv0 = xr[l];
    float4 xv1 = xr[64 + l];

    float acc[16];
#pragma unroll
    for (int f = 0; f < 8; ++f) {
        const float4* w = (const float4*)(W12 + f * ND);
        float4 a = w[l], b = w[64 + l];
        float s = a.x * xv0.x;
        s = fmaf(a.y, xv0.y, s); s = fmaf(a.z, xv0.z, s); s = fmaf(a.w, xv0.w, s);
        s = fmaf(b.x, xv1.x, s); s = fmaf(b.y, xv1.y, s); s = fmaf(b.z, xv1.z, s);
        s = fmaf(b.w, xv1.w, s);
        acc[f] = s;
        const float4* dw = (const float4*)(dW12 + f * ND);
        float4 c = dw[l], d = dw[64 + l];
        float u = c.x * xv0.x;
        u = fmaf(c.y, xv0.y, u); u = fmaf(c.z, xv0.z, u); u = fmaf(c.w, xv0.w, u);
        u = fmaf(d.x, xv1.x, u); u = fmaf(d.y, xv1.y, u); u = fmaf(d.z, xv1.z, u);
        u = fmaf(d.w, xv1.w, u);
        acc[8 + f] = u;
    }
#pragma unroll
    for (int f = 0; f < 16; ++f) acc[f] = dpp_sum64(acc[f]);

    if (l == 63) {
        float4* o = (float4*)(PT + (size_t)bt * 16);
#pragma unroll
        for (int g = 0; g < 4; ++g)
            o[g] = make_float4(acc[g], acc[g + 4], acc[8 + g], acc[12 + g]);
    }
}

// ---------------------------------------------------------------------------
// Kernel B: FUSED producer+consumer (R12 champion structure), one 8-wave
// block per batch element. Waves 0-3 (producer, factor pair {g,g+4}):
// layer-1 recurrence at step i; the recurrence-critical U12/dU12 dots run
// FIRST, then gates + h1 write; the W22/dW22 projections (only needed at
// the next barrier via mr) run AFTER, in the pre-barrier shadow.
// Waves 4-7 (consumer): layer-2 recurrence at s = i-2 reading mr[s&1].
// ONE lgkm-only barrier per iteration; fire-and-forget out stores.
// ---------------------------------------------------------------------------
__global__ __launch_bounds__(512, 2) void lstm_fused_kernel(
    const float* __restrict__ PT, const float* __restrict__ h0,
    const float* __restrict__ c0,
    const float* __restrict__ W11, const float* __restrict__ U11,
    const float* __restrict__ dW11, const float* __restrict__ dU11,
    const float* __restrict__ U12, const float* __restrict__ dU12,
    const float* __restrict__ b11, const float* __restrict__ b12,
    const float* __restrict__ W21, const float* __restrict__ U21,
    const float* __restrict__ dW21, const float* __restrict__ dU21,
    const float* __restrict__ W22, const float* __restrict__ dW22,
    const float* __restrict__ U22, const float* __restrict__ dU22,
    const float* __restrict__ b21, const float* __restrict__ b22,
    float* __restrict__ out) {
    int b = blockIdx.x;
    int tid = threadIdx.x;
    int wv = tid >> 6;
    int l = tid & 63;
    int g = wv & 3;                 // factor pair {g, g+4}
    int kb = 32 * (l & 15) + (l >> 4);
    int rA = 8 * l + g, rB = 8 * l + g + 4;   // owned rows

    __shared__ float Ps[NS * 16];   // 32 KB staged P slice
    __shared__ float hb1[2][NH];    // layer-1 h (permuted slots)
    __shared__ float hb2[2][NH];    // layer-2 h
    __shared__ float mr[2][16];     // L1->L2 projection handoff

    // stage P (all 8 waves)
    {
        const float4* src = (const float4*)(PT + (size_t)b * NS * 16);
        float4* dst = (float4*)Ps;
#pragma unroll
        for (int i = 0; i < 4; ++i) dst[tid + i * 512] = src[tid + i * 512];
    }

    float* hn = out + (size_t)NB * NS * NH;
    float* cn = hn + (size_t)2 * NB * NH;
    const float SQ[4] = {-L2E, -L2E, 2.0f * L2E, -L2E};

    if (wv < 4) {
        // ========================= PRODUCER (layer 1) ======================
        float wU0[8], wU1[8], wD0[8], wD1[8], wW0[8], wW1[8], wV0[8], wV1[8];
        LW(U12, g, wU0)      LW(U12, g + 4, wU1)
        LW(dU12, g, wD0)     LW(dU12, g + 4, wD1)
        LW(W22, g, wW0)      LW(W22, g + 4, wW1)
        LW(dW22, g, wV0)     LW(dW22, g + 4, wV1)

        float cw[4], cdw[4], cu[4], cdu[4], bbA[4], bbB[4];
#pragma unroll
        for (int q = 0; q < 4; ++q) {
            cw[q] = W11[q * 64 + l] * SQ[q];
            cdw[q] = dW11[q * 64 + l] * SQ[q];
            cu[q] = U11[q * 64 + l] * SQ[q];
            cdu[q] = dU11[q * 64 + l] * SQ[q];
            bbA[q] = (b11[q * NH + rA] + b12[q * NH + rA]) * SQ[q];
            bbB[q] = (b11[q * NH + rB] + b12[q * NH + rB]) * SQ[q];
        }
        float hA = h0[(size_t)b * NH + rA], hB = h0[(size_t)b * NH + rB];
        float cA = c0[(size_t)b * NH + rA], cB = c0[(size_t)b * NH + rB];
        hb1[0][64 * g + l] = hA;
        hb1[0][64 * (g + 4) + l] = hB;
        wg_barrier();

        for (int i = 0; i <= NS + 1; ++i) {
            if (i <= NS) {
                float4 x0 = *(const float4*)&hb1[i & 1][4 * l];
                float4 x1 = *(const float4*)&hb1[i & 1][256 + 4 * l];
                if (i < NS) {
                    // CRITICAL CHAIN first: U dots -> gates -> h1 write
                    float rUa = dpp_sum64(dot8s(wU0, x0, x1));
                    float rUb = dpp_sum64(dot8s(wU1, x0, x1));
                    float rDa = dpp_sum64(dot8s(wD0, x0, x1));
                    float rDb = dpp_sum64(dot8s(wD1, x0, x1));
                    float m3A = bcast63(rUa), m3B = bcast63(rUb);
                    float m4A = bcast63(rDa), m4B = bcast63(rDb);
                    float4 pv = *(const float4*)&Ps[i * 16 + 4 * g];
                    GATEX(pv.x, pv.z, m3A, m4A, bbA, cA, hA)
                    GATEX(pv.y, pv.w, m3B, m4B, bbB, cB, hB)
                    hb1[(i + 1) & 1][64 * g + l] = hA;
                    hb1[(i + 1) & 1][64 * (g + 4) + l] = hB;
                }
                // OFF-CHAIN: W22/dW22 projections of h1(i) (x regs live),
                // needed only at the next barrier via mr.
                float rWa = dpp_sum64(dot8s(wW0, x0, x1));
                float rWb = dpp_sum64(dot8s(wW1, x0, x1));
                float rVa = dpp_sum64(dot8s(wV0, x0, x1));
                float rVb = dpp_sum64(dot8s(wV1, x0, x1));
                if (i > 0 && l == 63) {
                    *(float2*)&mr[(i - 1) & 1][2 * g] = make_float2(rWa, rVa);
                    *(float2*)&mr[(i - 1) & 1][8 + 2 * g] = make_float2(rWb, rVb);
                }
            }
            wg_barrier();
        }
        hn[(size_t)b * NH + rA] = hA;
        hn[(size_t)b * NH + rB] = hB;
        cn[(size_t)b * NH + rA] = cA;
        cn[(size_t)b * NH + rB] = cB;
    } else {
        // ========================= CONSUMER (layer 2) ======================
        float wU0[8], wU1[8], wD0[8], wD1[8];
        LW(U22, g, wU0)      LW(U22, g + 4, wU1)
        LW(dU22, g, wD0)     LW(dU22, g + 4, wD1)

        float cw[4], cdw[4], cu[4], cdu[4], bbA[4], bbB[4];
#pragma unroll
        for (int q = 0; q < 4; ++q) {
            cw[q] = W21[q * 64 + l] * SQ[q];
            cdw[q] = dW21[q * 64 + l] * SQ[q];
            cu[q] = U21[q * 64 + l] * SQ[q];
            cdu[q] = dU21[q * 64 + l] * SQ[q];
            bbA[q] = (b21[q * NH + rA] + b22[q * NH + rA]) * SQ[q];
            bbB[q] = (b21[q * NH + rB] + b22[q * NH + rB]) * SQ[q];
        }
        const float* h0p = h0 + (size_t)NB * NH + (size_t)b * NH;
        const float* c0p = c0 + (size_t)NB * NH + (size_t)b * NH;
        float hA = h0p[rA], hB = h0p[rB];
        float cA = c0p[rA], cB = c0p[rB];
        hb2[0][64 * g + l] = hA;
        hb2[0][64 * (g + 4) + l] = hB;
        wg_barrier();

        float* outb = out + (size_t)b * NS * NH;
        for (int i = 0; i <= NS + 1; ++i) {
            int s = i - 2;
            if (s >= 0) {
                float2 mvA = *(const float2*)&mr[s & 1][2 * g];      // {W g, dW g}
                float2 mvB = *(const float2*)&mr[s & 1][8 + 2 * g];  // {W g+4, dW g+4}
                float4 y0 = *(const float4*)&hb2[s & 1][4 * l];
                float4 y1 = *(const float4*)&hb2[s & 1][256 + 4 * l];
                float rUa = dpp_sum64(dot8s(wU0, y0, y1));
                float rUb = dpp_sum64(dot8s(wU1, y0, y1));
                float rDa = dpp_sum64(dot8s(wD0, y0, y1));
                float rDb = dpp_sum64(dot8s(wD1, y0, y1));
                float m5A = bcast63(rUa), m5B = bcast63(rUb);
                float m6A = bcast63(rDa), m6B = bcast63(rDb);
                GATEX(mvA.x, mvA.y, m5A, m6A, bbA, cA, hA)
                GATEX(mvB.x, mvB.y, m5B, m6B, bbB, cB, hB)
                hb2[(s + 1) & 1][64 * g + l] = hA;
                hb2[(s + 1) & 1][64 * (g + 4) + l] = hB;
                outb[(size_t)s * NH + rA] = hA;   // fire-and-forget
                outb[(size_t)s * NH + rB] = hB;
            }
            wg_barrier();
        }
        hn[(size_t)NB * NH + (size_t)b * NH + rA] = hA;
        hn[(size_t)NB * NH + (size_t)b * NH + rB] = hB;
        cn[(size_t)NB * NH + (size_t)b * NH + rA] = cA;
        cn[(size_t)NB * NH + (size_t)b * NH + rB] = cB;
    }
}

extern "C" void kernel_launch(void* const* d_in, const int* in_sizes, int n_in,
                              void* d_out, int out_size, void* d_ws, size_t ws_size,
                              hipStream_t stream) {
    const float* x = (const float*)d_in[0];
    const float* h0 = (const float*)d_in[1];
    const float* c0 = (const float*)d_in[2];
    const float* W11 = (const float*)d_in[3];
    const float* W12 = (const float*)d_in[4];
    const float* U11 = (const float*)d_in[5];
    const float* U12 = (const float*)d_in[6];
    const float* dW11 = (const float*)d_in[7];
    const float* dW12 = (const float*)d_in[8];
    const float* dU11 = (const float*)d_in[9];
    const float* dU12 = (const float*)d_in[10];
    const float* b11 = (const float*)d_in[11];
    const float* b12 = (const float*)d_in[12];
    const float* W21 = (const float*)d_in[13];
    const float* W22 = (const float*)d_in[14];
    const float* U21 = (const float*)d_in[15];
    const float* U22 = (const float*)d_in[16];
    const float* dW21 = (const float*)d_in[17];
    const float* dW22 = (const float*)d_in[18];
    const float* dU21 = (const float*)d_in[19];
    const float* dU22 = (const float*)d_in[20];
    const float* b21 = (const float*)d_in[21];
    const float* b22 = (const float*)d_in[22];

    float* PT = (float*)d_ws;   // 2 MB
    float* out = (float*)d_out;

    hipLaunchKernelGGL(precomp_kernel, dim3(NB * NS), dim3(64), 0, stream,
                       x, W12, dW12, PT);
    hipLaunchKernelGGL(lstm_fused_kernel, dim3(NB), dim3(512), 0, stream,
                       PT, h0, c0,
                       W11, U11, dW11, dU11, U12, dU12, b11, b12,
                       W21, U21, dW21, dU21, W22, dW22, U22, dU22, b21, b22,
                       out);
}

// Round 18
// 407.081 us; speedup vs baseline: 1.1796x; 1.0437x over previous
//
#include <hip/hip_runtime.h>
#include <math.h>

#define NB 64       // batch
#define NS 512      // seq len
#define ND 512      // input dim
#define NH 512      // hidden
#define L2E 1.4426950408889634f

// 64-lane sum via DPP (VALU only). Total lands in lane 63.
__device__ __forceinline__ float dpp_sum64(float x) {
    x += __int_as_float(__builtin_amdgcn_update_dpp(0, __float_as_int(x), 0x111, 0xf, 0xf, true)); // row_shr:1
    x += __int_as_float(__builtin_amdgcn_update_dpp(0, __float_as_int(x), 0x112, 0xf, 0xf, true)); // row_shr:2
    x += __int_as_float(__builtin_amdgcn_update_dpp(0, __float_as_int(x), 0x114, 0xf, 0xf, true)); // row_shr:4
    x += __int_as_float(__builtin_amdgcn_update_dpp(0, __float_as_int(x), 0x118, 0xf, 0xf, true)); // row_shr:8
    x += __int_as_float(__builtin_amdgcn_update_dpp(0, __float_as_int(x), 0x142, 0xa, 0xf, true)); // row_bcast:15
    x += __int_as_float(__builtin_amdgcn_update_dpp(0, __float_as_int(x), 0x143, 0xc, 0xf, true)); // row_bcast:31
    return x;
}

__device__ __forceinline__ float bcast63(float x) {
    return __int_as_float(__builtin_amdgcn_readlane(__float_as_int(x), 63));
}
__device__ __forceinline__ float rcp_fast(float x) { return __builtin_amdgcn_rcpf(x); }
__device__ __forceinline__ float exp2_fast(float x) {
    float r;
    asm("v_exp_f32 %0, %1" : "=v"(r) : "v"(x));
    return r;
}
__device__ __forceinline__ void wg_barrier() {
    asm volatile("s_waitcnt lgkmcnt(0)\n\ts_barrier" ::: "memory");
}

// packed f16 dot2 with f32 accumulate: d = a.h0*b.h0 + a.h1*b.h1 + c
__device__ __forceinline__ float fdot2a(unsigned int a, unsigned int b, float c) {
    float d;
    asm("v_dot2_f32_f16 %0, %1, %2, %3" : "=v"(d) : "v"(a), "v"(b), "v"(c));
    return d;
}

// 8-elem dot: 4 packed-f16 weight words vs a float4 containing 8 f16 h-values
__device__ __forceinline__ float dot8h(const unsigned int* w, float4 xv) {
    float r = fdot2a(w[0], __float_as_uint(xv.x), 0.0f);
    r = fdot2a(w[1], __float_as_uint(xv.y), r);
    r = fdot2a(w[2], __float_as_uint(xv.z), r);
    r = fdot2a(w[3], __float_as_uint(xv.w), r);
    return r;
}

// LDS slot s holds h-row 8*(s&63) + (s>>6); thread l reads slots 8l..8l+7
#define ROWOF(s) (8 * ((s) & 63) + ((s) >> 6))
// gather factor row f of mat into 4 packed-f16 words matching the read order
#define LWH(mat, f, arr)                                                      \
    {                                                                         \
        const float* M = (mat) + (f) * NH;                                    \
        _Pragma("unroll")                                                     \
        for (int j = 0; j < 4; ++j) {                                         \
            union { _Float16 h[2]; unsigned int u; } pk_;                     \
            int s0 = 8 * l + 2 * j;                                           \
            pk_.h[0] = (_Float16)M[ROWOF(s0)];                                \
            pk_.h[1] = (_Float16)M[ROWOF(s0 + 1)];                            \
            arr[j] = pk_.u;                                                   \
        }                                                                     \
    }

// one LSTM row update; coefficients pre-scaled by {-L2E,-L2E,+2L2E,-L2E}:
//   sigm -> 1/(1+2^g), tanh -> 1-2/(1+2^g)
#define GATEX(t1, t2, m3, m4, bb, cS, hS)                                     \
    {                                                                         \
        float g0 = fmaf(cw[0], (t1), fmaf(cdw[0], (t2), fmaf(cu[0], (m3), fmaf(cdu[0], (m4), bb[0])))); \
        float g1 = fmaf(cw[1], (t1), fmaf(cdw[1], (t2), fmaf(cu[1], (m3), fmaf(cdu[1], (m4), bb[1])))); \
        float g2 = fmaf(cw[2], (t1), fmaf(cdw[2], (t2), fmaf(cu[2], (m3), fmaf(cdu[2], (m4), bb[2])))); \
        float g3 = fmaf(cw[3], (t1), fmaf(cdw[3], (t2), fmaf(cu[3], (m3), fmaf(cdu[3], (m4), bb[3])))); \
        float ig = rcp_fast(1.0f + exp2_fast(g0));                            \
        float fg = rcp_fast(1.0f + exp2_fast(g1));                            \
        float gg = fmaf(-2.0f, rcp_fast(1.0f + exp2_fast(g2)), 1.0f);         \
        float og = rcp_fast(1.0f + exp2_fast(g3));                            \
        cS = fmaf(fg, cS, ig * gg);                                           \
        hS = og * fmaf(-2.0f, rcp_fast(1.0f + exp2_fast(cS * (2.0f * L2E))), 1.0f); \
    }

// ---------------------------------------------------------------------------
// Kernel A: PT[bt][g] = float4{(W12@x)[g], (W12@x)[g+4], (dW12@x)[g],
// (dW12@x)[g+4]} for g = 0..3 (producer wave-g layout) — same as R12.
// ---------------------------------------------------------------------------
__global__ __launch_bounds__(64) void precomp_kernel(
    const float* __restrict__ x, const float* __restrict__ W12,
    const float* __restrict__ dW12, float* __restrict__ PT) {
    int bt = blockIdx.x;
    int l = threadIdx.x;
    const float4* xr = (const float4*)(x + (size_t)bt * ND);
    float4 xv0 = xr[l];
    float4 xv1 = xr[64 + l];

    float acc[16];
#pragma unroll
    for (int f = 0; f < 8; ++f) {
        const float4* w = (const float4*)(W12 + f * ND);
        float4 a = w[l], b = w[64 + l];
        float s = a.x * xv0.x;
        s = fmaf(a.y, xv0.y, s); s = fmaf(a.z, xv0.z, s); s = fmaf(a.w, xv0.w, s);
        s = fmaf(b.x, xv1.x, s); s = fmaf(b.y, xv1.y, s); s = fmaf(b.z, xv1.z, s);
        s = fmaf(b.w, xv1.w, s);
        acc[f] = s;
        const float4* dw = (const float4*)(dW12 + f * ND);
        float4 c = dw[l], d = dw[64 + l];
        float u = c.x * xv0.x;
        u = fmaf(c.y, xv0.y, u); u = fmaf(c.z, xv0.z, u); u = fmaf(c.w, xv0.w, u);
        u = fmaf(d.x, xv1.x, u); u = fmaf(d.y, xv1.y, u); u = fmaf(d.z, xv1.z, u);
        u = fmaf(d.w, xv1.w, u);
        acc[8 + f] = u;
    }
#pragma unroll
    for (int f = 0; f < 16; ++f) acc[f] = dpp_sum64(acc[f]);

    if (l == 63) {
        float4* o = (float4*)(PT + (size_t)bt * 16);
#pragma unroll
        for (int g = 0; g < 4; ++g)
            o[g] = make_float4(acc[g], acc[g + 4], acc[8 + g], acc[12 + g]);
    }
}

// ---------------------------------------------------------------------------
// Kernel B: FUSED producer+consumer (R12 champion structure) with f16
// packed dots. h state lives in LDS as f16: one ds_read_b128 delivers all
// 8 dot operands pre-paired for v_dot2_f32_f16 (f32 accumulate).
// Waves 0-3 (producer, factors {g,g+4}): layer-1 recurrence + W22/dW22
// projections -> mr[(i-1)&1]. Waves 4-7 (consumer): layer-2 at s = i-2.
// ONE lgkm-only barrier per iteration; fire-and-forget out stores.
// ---------------------------------------------------------------------------
__global__ __launch_bounds__(512, 2) void lstm_fused_kernel(
    const float* __restrict__ PT, const float* __restrict__ h0,
    const float* __restrict__ c0,
    const float* __restrict__ W11, const float* __restrict__ U11,
    const float* __restrict__ dW11, const float* __restrict__ dU11,
    const float* __restrict__ U12, const float* __restrict__ dU12,
    const float* __restrict__ b11, const float* __restrict__ b12,
    const float* __restrict__ W21, const float* __restrict__ U21,
    const float* __restrict__ dW21, const float* __restrict__ dU21,
    const float* __restrict__ W22, const float* __restrict__ dW22,
    const float* __restrict__ U22, const float* __restrict__ dU22,
    const float* __restrict__ b21, const float* __restrict__ b22,
    float* __restrict__ out) {
    int b = blockIdx.x;
    int tid = threadIdx.x;
    int wv = tid >> 6;
    int l = tid & 63;
    int g = wv & 3;                 // factor pair {g, g+4}
    int rA = 8 * l + g, rB = 8 * l + g + 4;   // owned rows

    __shared__ float Ps[NS * 16];        // 32 KB staged P slice
    __shared__ _Float16 hb1[2][NH];      // layer-1 h (f16, permuted slots)
    __shared__ _Float16 hb2[2][NH];      // layer-2 h (f16)
    __shared__ float mr[2][16];          // L1->L2 projection handoff (f32)

    // stage P (all 8 waves)
    {
        const float4* src = (const float4*)(PT + (size_t)b * NS * 16);
        float4* dst = (float4*)Ps;
#pragma unroll
        for (int i = 0; i < 4; ++i) dst[tid + i * 512] = src[tid + i * 512];
    }

    float* hn = out + (size_t)NB * NS * NH;
    float* cn = hn + (size_t)2 * NB * NH;
    const float SQ[4] = {-L2E, -L2E, 2.0f * L2E, -L2E};

    if (wv < 4) {
        // ========================= PRODUCER (layer 1) ======================
        unsigned int wU0[4], wU1[4], wD0[4], wD1[4], wW0[4], wW1[4], wV0[4], wV1[4];
        LWH(U12, g, wU0)      LWH(U12, g + 4, wU1)
        LWH(dU12, g, wD0)     LWH(dU12, g + 4, wD1)
        LWH(W22, g, wW0)      LWH(W22, g + 4, wW1)
        LWH(dW22, g, wV0)     LWH(dW22, g + 4, wV1)

        float cw[4], cdw[4], cu[4], cdu[4], bbA[4], bbB[4];
#pragma unroll
        for (int q = 0; q < 4; ++q) {
            cw[q] = W11[q * 64 + l] * SQ[q];
            cdw[q] = dW11[q * 64 + l] * SQ[q];
            cu[q] = U11[q * 64 + l] * SQ[q];
            cdu[q] = dU11[q * 64 + l] * SQ[q];
            bbA[q] = (b11[q * NH + rA] + b12[q * NH + rA]) * SQ[q];
            bbB[q] = (b11[q * NH + rB] + b12[q * NH + rB]) * SQ[q];
        }
        float hA = h0[(size_t)b * NH + rA], hB = h0[(size_t)b * NH + rB];
        float cA = c0[(size_t)b * NH + rA], cB = c0[(size_t)b * NH + rB];
        hb1[0][64 * g + l] = (_Float16)hA;
        hb1[0][64 * (g + 4) + l] = (_Float16)hB;
        wg_barrier();

        for (int i = 0; i <= NS + 1; ++i) {
            if (i <= NS) {
                float4 xv = *(const float4*)&hb1[i & 1][8 * l];
                // projections of h1(i) -> m record for step i-1
                float rWa = dpp_sum64(dot8h(wW0, xv));
                float rWb = dpp_sum64(dot8h(wW1, xv));
                float rVa = dpp_sum64(dot8h(wV0, xv));
                float rVb = dpp_sum64(dot8h(wV1, xv));
                if (i > 0 && l == 63)
                    *(float4*)&mr[(i - 1) & 1][4 * g] =
                        make_float4(rWa, rWb, rVa, rVb);
                if (i < NS) {
                    float rUa = dpp_sum64(dot8h(wU0, xv));
                    float rUb = dpp_sum64(dot8h(wU1, xv));
                    float rDa = dpp_sum64(dot8h(wD0, xv));
                    float rDb = dpp_sum64(dot8h(wD1, xv));
                    float m3A = bcast63(rUa), m3B = bcast63(rUb);
                    float m4A = bcast63(rDa), m4B = bcast63(rDb);
                    float4 pv = *(const float4*)&Ps[i * 16 + 4 * g];
                    GATEX(pv.x, pv.z, m3A, m4A, bbA, cA, hA)
                    GATEX(pv.y, pv.w, m3B, m4B, bbB, cB, hB)
                    hb1[(i + 1) & 1][64 * g + l] = (_Float16)hA;
                    hb1[(i + 1) & 1][64 * (g + 4) + l] = (_Float16)hB;
                }
            }
            wg_barrier();
        }
        hn[(size_t)b * NH + rA] = hA;
        hn[(size_t)b * NH + rB] = hB;
        cn[(size_t)b * NH + rA] = cA;
        cn[(size_t)b * NH + rB] = cB;
    } else {
        // ========================= CONSUMER (layer 2) ======================
        unsigned int wU0[4], wU1[4], wD0[4], wD1[4];
        LWH(U22, g, wU0)      LWH(U22, g + 4, wU1)
        LWH(dU22, g, wD0)     LWH(dU22, g + 4, wD1)

        float cw[4], cdw[4], cu[4], cdu[4], bbA[4], bbB[4];
#pragma unroll
        for (int q = 0; q < 4; ++q) {
            cw[q] = W21[q * 64 + l] * SQ[q];
            cdw[q] = dW21[q * 64 + l] * SQ[q];
            cu[q] = U21[q * 64 + l] * SQ[q];
            cdu[q] = dU21[q * 64 + l] * SQ[q];
            bbA[q] = (b21[q * NH + rA] + b22[q * NH + rA]) * SQ[q];
            bbB[q] = (b21[q * NH + rB] + b22[q * NH + rB]) * SQ[q];
        }
        const float* h0p = h0 + (size_t)NB * NH + (size_t)b * NH;
        const float* c0p = c0 + (size_t)NB * NH + (size_t)b * NH;
        float hA = h0p[rA], hB = h0p[rB];
        float cA = c0p[rA], cB = c0p[rB];
        hb2[0][64 * g + l] = (_Float16)hA;
        hb2[0][64 * (g + 4) + l] = (_Float16)hB;
        wg_barrier();

        float* outb = out + (size_t)b * NS * NH;
        for (int i = 0; i <= NS + 1; ++i) {
            int s = i - 2;
            if (s >= 0) {
                float4 mv = *(const float4*)&mr[s & 1][4 * g];  // {Wg,Wg4,dWg,dWg4}
                float4 yv = *(const float4*)&hb2[s & 1][8 * l];
                float rUa = dpp_sum64(dot8h(wU0, yv));
                float rUb = dpp_sum64(dot8h(wU1, yv));
                float rDa = dpp_sum64(dot8h(wD0, yv));
                float rDb = dpp_sum64(dot8h(wD1, yv));
                float m5A = bcast63(rUa), m5B = bcast63(rUb);
                float m6A = bcast63(rDa), m6B = bcast63(rDb);
                GATEX(mv.x, mv.z, m5A, m6A, bbA, cA, hA)
                GATEX(mv.y, mv.w, m5B, m6B, bbB, cB, hB)
                hb2[(s + 1) & 1][64 * g + l] = (_Float16)hA;
                hb2[(s + 1) & 1][64 * (g + 4) + l] = (_Float16)hB;
                outb[(size_t)s * NH + rA] = hA;   // fire-and-forget
                outb[(size_t)s * NH + rB] = hB;
            }
            wg_barrier();
        }
        hn[(size_t)NB * NH + (size_t)b * NH + rA] = hA;
        hn[(size_t)NB * NH + (size_t)b * NH + rB] = hB;
        cn[(size_t)NB * NH + (size_t)b * NH + rA] = cA;
        cn[(size_t)NB * NH + (size_t)b * NH + rB] = cB;
    }
}

extern "C" void kernel_launch(void* const* d_in, const int* in_sizes, int n_in,
                              void* d_out, int out_size, void* d_ws, size_t ws_size,
                              hipStream_t stream) {
    const float* x = (const float*)d_in[0];
    const float* h0 = (const float*)d_in[1];
    const float* c0 = (const float*)d_in[2];
    const float* W11 = (const float*)d_in[3];
    const float* W12 = (const float*)d_in[4];
    const float* U11 = (const float*)d_in[5];
    const float* U12 = (const float*)d_in[6];
    const float* dW11 = (const float*)d_in[7];
    const float* dW12 = (const float*)d_in[8];
    const float* dU11 = (const float*)d_in[9];
    const float* dU12 = (const float*)d_in[10];
    const float* b11 = (const float*)d_in[11];
    const float* b12 = (const float*)d_in[12];
    const float* W21 = (const float*)d_in[13];
    const float* W22 = (const float*)d_in[14];
    const float* U21 = (const float*)d_in[15];
    const float* U22 = (const float*)d_in[16];
    const float* dW21 = (const float*)d_in[17];
    const float* dW22 = (const float*)d_in[18];
    const float* dU21 = (const float*)d_in[19];
    const float* dU22 = (const float*)d_in[20];
    const float* b21 = (const float*)d_in[21];
    const float* b22 = (const float*)d_in[22];

    float* PT = (float*)d_ws;   // 2 MB
    float* out = (float*)d_out;

    hipLaunchKernelGGL(precomp_kernel, dim3(NB * NS), dim3(64), 0, stream,
                       x, W12, dW12, PT);
    hipLaunchKernelGGL(lstm_fused_kernel, dim3(NB), dim3(512), 0, stream,
                       PT, h0, c0,
                       W11, U11, dW11, dU11, U12, dU12, b11, b12,
                       W21, U21, dW21, dU21, W22, dW22, U22, dU22, b21, b22,
                       out);
}

// Round 19
// 398.641 us; speedup vs baseline: 1.2046x; 1.0212x over previous
//
#include <hip/hip_runtime.h>
#include <math.h>

#define NB 64       // batch
#define NS 512      // seq len
#define ND 512      // input dim
#define NH 512      // hidden
#define L2E 1.4426950408889634f

// 64-lane sum via DPP (VALU only). Total lands in lane 63.
__device__ __forceinline__ float dpp_sum64(float x) {
    x += __int_as_float(__builtin_amdgcn_update_dpp(0, __float_as_int(x), 0x111, 0xf, 0xf, true)); // row_shr:1
    x += __int_as_float(__builtin_amdgcn_update_dpp(0, __float_as_int(x), 0x112, 0xf, 0xf, true)); // row_shr:2
    x += __int_as_float(__builtin_amdgcn_update_dpp(0, __float_as_int(x), 0x114, 0xf, 0xf, true)); // row_shr:4
    x += __int_as_float(__builtin_amdgcn_update_dpp(0, __float_as_int(x), 0x118, 0xf, 0xf, true)); // row_shr:8
    x += __int_as_float(__builtin_amdgcn_update_dpp(0, __float_as_int(x), 0x142, 0xa, 0xf, true)); // row_bcast:15
    x += __int_as_float(__builtin_amdgcn_update_dpp(0, __float_as_int(x), 0x143, 0xc, 0xf, true)); // row_bcast:31
    return x;
}

__device__ __forceinline__ float bcast63(float x) {
    return __int_as_float(__builtin_amdgcn_readlane(__float_as_int(x), 63));
}
__device__ __forceinline__ float rcp_fast(float x) { return __builtin_amdgcn_rcpf(x); }
__device__ __forceinline__ float exp2_fast(float x) {
    float r;
    asm("v_exp_f32 %0, %1" : "=v"(r) : "v"(x));
    return r;
}
__device__ __forceinline__ void wg_barrier() {
    asm volatile("s_waitcnt lgkmcnt(0)\n\ts_barrier" ::: "memory");
}

// packed f16 dot2 with f32 accumulate: d = a.h0*b.h0 + a.h1*b.h1 + c
__device__ __forceinline__ float fdot2a(unsigned int a, unsigned int b, float c) {
    float d;
    asm("v_dot2_f32_f16 %0, %1, %2, %3" : "=v"(d) : "v"(a), "v"(b), "v"(c));
    return d;
}

// 8-elem dot: 4 packed-f16 weight words vs a float4 containing 8 f16 h-values
__device__ __forceinline__ float dot8h(const unsigned int* w, float4 xv) {
    float r = fdot2a(w[0], __float_as_uint(xv.x), 0.0f);
    r = fdot2a(w[1], __float_as_uint(xv.y), r);
    r = fdot2a(w[2], __float_as_uint(xv.z), r);
    r = fdot2a(w[3], __float_as_uint(xv.w), r);
    return r;
}

// LDS slot s holds h-row 8*(s&63) + (s>>6); thread l reads slots 8l..8l+7
#define ROWOF(s) (8 * ((s) & 63) + ((s) >> 6))
// gather factor row f of mat into 4 packed-f16 words matching the read order
#define LWH(mat, f, arr)                                                      \
    {                                                                         \
        const float* M = (mat) + (f) * NH;                                    \
        _Pragma("unroll")                                                     \
        for (int j = 0; j < 4; ++j) {                                         \
            union { _Float16 h[2]; unsigned int u; } pk_;                     \
            int s0 = 8 * l + 2 * j;                                           \
            pk_.h[0] = (_Float16)M[ROWOF(s0)];                                \
            pk_.h[1] = (_Float16)M[ROWOF(s0 + 1)];                            \
            arr[j] = pk_.u;                                                   \
        }                                                                     \
    }

// one LSTM row update with DIVISION-FOLDED activations (2 rcp, was 5).
// coefficients pre-scaled by {-L2E,-L2E,+2L2E,-L2E}:
//   A=2^g0 -> ig=1/(1+A); F=2^g1 -> fg=1/(1+F); B=2^g2 -> gg=(B-1)/(1+B);
//   D=2^g3 -> og=1/(1+D)
//   c' = fg*c + ig*gg = [c*(1+A)(1+B) + (B-1)(1+F)] / [(1+F)(1+A)(1+B)]
//   h  = og*tanh(c')  = (E-1) / [(1+D)(1+E)],  E = 2^(2*L2E*c')
#define GATEX(t1, t2, m3, m4, bb, cS, hS)                                     \
    {                                                                         \
        float g0 = fmaf(cw[0], (t1), fmaf(cdw[0], (t2), fmaf(cu[0], (m3), fmaf(cdu[0], (m4), bb[0])))); \
        float g1 = fmaf(cw[1], (t1), fmaf(cdw[1], (t2), fmaf(cu[1], (m3), fmaf(cdu[1], (m4), bb[1])))); \
        float g2 = fmaf(cw[2], (t1), fmaf(cdw[2], (t2), fmaf(cu[2], (m3), fmaf(cdu[2], (m4), bb[2])))); \
        float g3 = fmaf(cw[3], (t1), fmaf(cdw[3], (t2), fmaf(cu[3], (m3), fmaf(cdu[3], (m4), bb[3])))); \
        float A_ = exp2_fast(g0);                                             \
        float F_ = exp2_fast(g1);                                             \
        float B_ = exp2_fast(g2);                                             \
        float D_ = exp2_fast(g3);                                             \
        float pA = 1.0f + A_, pF = 1.0f + F_, pB = 1.0f + B_;                 \
        float den1 = pF * (pA * pB);                                          \
        float num1 = fmaf(cS * pA, pB, (B_ - 1.0f) * pF);                     \
        cS = num1 * rcp_fast(den1);                                           \
        float E_ = exp2_fast(cS * (2.0f * L2E));                              \
        float pD = 1.0f + D_, pE = 1.0f + E_;                                 \
        hS = (E_ - 1.0f) * rcp_fast(pD * pE);                                 \
    }

// ---------------------------------------------------------------------------
// Kernel A: PT[bt][g] = float4{(W12@x)[g], (W12@x)[g+4], (dW12@x)[g],
// (dW12@x)[g+4]} for g = 0..3 (producer wave-g layout)
// ---------------------------------------------------------------------------
__global__ __launch_bounds__(64) void precomp_kernel(
    const float* __restrict__ x, const float* __restrict__ W12,
    const float* __restrict__ dW12, float* __restrict__ PT) {
    int bt = blockIdx.x;
    int l = threadIdx.x;
    const float4* xr = (const float4*)(x + (size_t)bt * ND);
    float4 xv0 = xr[l];
    float4 xv1 = xr[64 + l];

    float acc[16];
#pragma unroll
    for (int f = 0; f < 8; ++f) {
        const float4* w = (const float4*)(W12 + f * ND);
        float4 a = w[l], b = w[64 + l];
        float s = a.x * xv0.x;
        s = fmaf(a.y, xv0.y, s); s = fmaf(a.z, xv0.z, s); s = fmaf(a.w, xv0.w, s);
        s = fmaf(b.x, xv1.x, s); s = fmaf(b.y, xv1.y, s); s = fmaf(b.z, xv1.z, s);
        s = fmaf(b.w, xv1.w, s);
        acc[f] = s;
        const float4* dw = (const float4*)(dW12 + f * ND);
        float4 c = dw[l], d = dw[64 + l];
        float u = c.x * xv0.x;
        u = fmaf(c.y, xv0.y, u); u = fmaf(c.z, xv0.z, u); u = fmaf(c.w, xv0.w, u);
        u = fmaf(d.x, xv1.x, u); u = fmaf(d.y, xv1.y, u); u = fmaf(d.z, xv1.z, u);
        u = fmaf(d.w, xv1.w, u);
        acc[8 + f] = u;
    }
#pragma unroll
    for (int f = 0; f < 16; ++f) acc[f] = dpp_sum64(acc[f]);

    if (l == 63) {
        float4* o = (float4*)(PT + (size_t)bt * 16);
#pragma unroll
        for (int g = 0; g < 4; ++g)
            o[g] = make_float4(acc[g], acc[g + 4], acc[8 + g], acc[12 + g]);
    }
}

// ---------------------------------------------------------------------------
// Kernel B: FUSED producer+consumer (R12/R18 champion structure) with f16
// packed dots and division-folded gates. h state lives in LDS as f16: one
// ds_read_b128 delivers all 8 dot operands pre-paired for v_dot2_f32_f16.
// Waves 0-3 (producer, factors {g,g+4}): layer-1 recurrence + W22/dW22
// projections -> mr[(i-1)&1]. Waves 4-7 (consumer): layer-2 at s = i-2.
// ONE lgkm-only barrier per iteration; fire-and-forget out stores.
// ---------------------------------------------------------------------------
__global__ __launch_bounds__(512, 2) void lstm_fused_kernel(
    const float* __restrict__ PT, const float* __restrict__ h0,
    const float* __restrict__ c0,
    const float* __restrict__ W11, const float* __restrict__ U11,
    const float* __restrict__ dW11, const float* __restrict__ dU11,
    const float* __restrict__ U12, const float* __restrict__ dU12,
    const float* __restrict__ b11, const float* __restrict__ b12,
    const float* __restrict__ W21, const float* __restrict__ U21,
    const float* __restrict__ dW21, const float* __restrict__ dU21,
    const float* __restrict__ W22, const float* __restrict__ dW22,
    const float* __restrict__ U22, const float* __restrict__ dU22,
    const float* __restrict__ b21, const float* __restrict__ b22,
    float* __restrict__ out) {
    int b = blockIdx.x;
    int tid = threadIdx.x;
    int wv = tid >> 6;
    int l = tid & 63;
    int g = wv & 3;                 // factor pair {g, g+4}
    int rA = 8 * l + g, rB = 8 * l + g + 4;   // owned rows

    __shared__ float Ps[NS * 16];        // 32 KB staged P slice
    __shared__ _Float16 hb1[2][NH];      // layer-1 h (f16, permuted slots)
    __shared__ _Float16 hb2[2][NH];      // layer-2 h (f16)
    __shared__ float mr[2][16];          // L1->L2 projection handoff (f32)

    // stage P (all 8 waves)
    {
        const float4* src = (const float4*)(PT + (size_t)b * NS * 16);
        float4* dst = (float4*)Ps;
#pragma unroll
        for (int i = 0; i < 4; ++i) dst[tid + i * 512] = src[tid + i * 512];
    }

    float* hn = out + (size_t)NB * NS * NH;
    float* cn = hn + (size_t)2 * NB * NH;
    const float SQ[4] = {-L2E, -L2E, 2.0f * L2E, -L2E};

    if (wv < 4) {
        // ========================= PRODUCER (layer 1) ======================
        unsigned int wU0[4], wU1[4], wD0[4], wD1[4], wW0[4], wW1[4], wV0[4], wV1[4];
        LWH(U12, g, wU0)      LWH(U12, g + 4, wU1)
        LWH(dU12, g, wD0)     LWH(dU12, g + 4, wD1)
        LWH(W22, g, wW0)      LWH(W22, g + 4, wW1)
        LWH(dW22, g, wV0)     LWH(dW22, g + 4, wV1)

        float cw[4], cdw[4], cu[4], cdu[4], bbA[4], bbB[4];
#pragma unroll
        for (int q = 0; q < 4; ++q) {
            cw[q] = W11[q * 64 + l] * SQ[q];
            cdw[q] = dW11[q * 64 + l] * SQ[q];
            cu[q] = U11[q * 64 + l] * SQ[q];
            cdu[q] = dU11[q * 64 + l] * SQ[q];
            bbA[q] = (b11[q * NH + rA] + b12[q * NH + rA]) * SQ[q];
            bbB[q] = (b11[q * NH + rB] + b12[q * NH + rB]) * SQ[q];
        }
        float hA = h0[(size_t)b * NH + rA], hB = h0[(size_t)b * NH + rB];
        float cA = c0[(size_t)b * NH + rA], cB = c0[(size_t)b * NH + rB];
        hb1[0][64 * g + l] = (_Float16)hA;
        hb1[0][64 * (g + 4) + l] = (_Float16)hB;
        wg_barrier();

        for (int i = 0; i <= NS + 1; ++i) {
            if (i <= NS) {
                float4 xv = *(const float4*)&hb1[i & 1][8 * l];
                // projections of h1(i) -> m record for step i-1
                float rWa = dpp_sum64(dot8h(wW0, xv));
                float rWb = dpp_sum64(dot8h(wW1, xv));
                float rVa = dpp_sum64(dot8h(wV0, xv));
                float rVb = dpp_sum64(dot8h(wV1, xv));
                if (i > 0 && l == 63)
                    *(float4*)&mr[(i - 1) & 1][4 * g] =
                        make_float4(rWa, rWb, rVa, rVb);
                if (i < NS) {
                    float rUa = dpp_sum64(dot8h(wU0, xv));
                    float rUb = dpp_sum64(dot8h(wU1, xv));
                    float rDa = dpp_sum64(dot8h(wD0, xv));
                    float rDb = dpp_sum64(dot8h(wD1, xv));
                    float m3A = bcast63(rUa), m3B = bcast63(rUb);
                    float m4A = bcast63(rDa), m4B = bcast63(rDb);
                    float4 pv = *(const float4*)&Ps[i * 16 + 4 * g];
                    GATEX(pv.x, pv.z, m3A, m4A, bbA, cA, hA)
                    GATEX(pv.y, pv.w, m3B, m4B, bbB, cB, hB)
                    hb1[(i + 1) & 1][64 * g + l] = (_Float16)hA;
                    hb1[(i + 1) & 1][64 * (g + 4) + l] = (_Float16)hB;
                }
            }
            wg_barrier();
        }
        hn[(size_t)b * NH + rA] = hA;
        hn[(size_t)b * NH + rB] = hB;
        cn[(size_t)b * NH + rA] = cA;
        cn[(size_t)b * NH + rB] = cB;
    } else {
        // ========================= CONSUMER (layer 2) ======================
        unsigned int wU0[4], wU1[4], wD0[4], wD1[4];
        LWH(U22, g, wU0)      LWH(U22, g + 4, wU1)
        LWH(dU22, g, wD0)     LWH(dU22, g + 4, wD1)

        float cw[4], cdw[4], cu[4], cdu[4], bbA[4], bbB[4];
#pragma unroll
        for (int q = 0; q < 4; ++q) {
            cw[q] = W21[q * 64 + l] * SQ[q];
            cdw[q] = dW21[q * 64 + l] * SQ[q];
            cu[q] = U21[q * 64 + l] * SQ[q];
            cdu[q] = dU21[q * 64 + l] * SQ[q];
            bbA[q] = (b21[q * NH + rA] + b22[q * NH + rA]) * SQ[q];
            bbB[q] = (b21[q * NH + rB] + b22[q * NH + rB]) * SQ[q];
        }
        const float* h0p = h0 + (size_t)NB * NH + (size_t)b * NH;
        const float* c0p = c0 + (size_t)NB * NH + (size_t)b * NH;
        float hA = h0p[rA], hB = h0p[rB];
        float cA = c0p[rA], cB = c0p[rB];
        hb2[0][64 * g + l] = (_Float16)hA;
        hb2[0][64 * (g + 4) + l] = (_Float16)hB;
        wg_barrier();

        float* outb = out + (size_t)b * NS * NH;
        for (int i = 0; i <= NS + 1; ++i) {
            int s = i - 2;
            if (s >= 0) {
                float4 mv = *(const float4*)&mr[s & 1][4 * g];  // {Wg,Wg4,dWg,dWg4}
                float4 yv = *(const float4*)&hb2[s & 1][8 * l];
                float rUa = dpp_sum64(dot8h(wU0, yv));
                float rUb = dpp_sum64(dot8h(wU1, yv));
                float rDa = dpp_sum64(dot8h(wD0, yv));
                float rDb = dpp_sum64(dot8h(wD1, yv));
                float m5A = bcast63(rUa), m5B = bcast63(rUb);
                float m6A = bcast63(rDa), m6B = bcast63(rDb);
                GATEX(mv.x, mv.z, m5A, m6A, bbA, cA, hA)
                GATEX(mv.y, mv.w, m5B, m6B, bbB, cB, hB)
                hb2[(s + 1) & 1][64 * g + l] = (_Float16)hA;
                hb2[(s + 1) & 1][64 * (g + 4) + l] = (_Float16)hB;
                outb[(size_t)s * NH + rA] = hA;   // fire-and-forget
                outb[(size_t)s * NH + rB] = hB;
            }
            wg_barrier();
        }
        hn[(size_t)NB * NH + (size_t)b * NH + rA] = hA;
        hn[(size_t)NB * NH + (size_t)b * NH + rB] = hB;
        cn[(size_t)NB * NH + (size_t)b * NH + rA] = cA;
        cn[(size_t)NB * NH + (size_t)b * NH + rB] = cB;
    }
}

extern "C" void kernel_launch(void* const* d_in, const int* in_sizes, int n_in,
                              void* d_out, int out_size, void* d_ws, size_t ws_size,
                              hipStream_t stream) {
    const float* x = (const float*)d_in[0];
    const float* h0 = (const float*)d_in[1];
    const float* c0 = (const float*)d_in[2];
    const float* W11 = (const float*)d_in[3];
    const float* W12 = (const float*)d_in[4];
    const float* U11 = (const float*)d_in[5];
    const float* U12 = (const float*)d_in[6];
    const float* dW11 = (const float*)d_in[7];
    const float* dW12 = (const float*)d_in[8];
    const float* dU11 = (const float*)d_in[9];
    const float* dU12 = (const float*)d_in[10];
    const float* b11 = (const float*)d_in[11];
    const float* b12 = (const float*)d_in[12];
    const float* W21 = (const float*)d_in[13];
    const float* W22 = (const float*)d_in[14];
    const float* U21 = (const float*)d_in[15];
    const float* U22 = (const float*)d_in[16];
    const float* dW21 = (const float*)d_in[17];
    const float* dW22 = (const float*)d_in[18];
    const float* dU21 = (const float*)d_in[19];
    const float* dU22 = (const float*)d_in[20];
    const float* b21 = (const float*)d_in[21];
    const float* b22 = (const float*)d_in[22];

    float* PT = (float*)d_ws;   // 2 MB
    float* out = (float*)d_out;

    hipLaunchKernelGGL(precomp_kernel, dim3(NB * NS), dim3(64), 0, stream,
                       x, W12, dW12, PT);
    hipLaunchKernelGGL(lstm_fused_kernel, dim3(NB), dim3(512), 0, stream,
                       PT, h0, c0,
                       W11, U11, dW11, dU11, U12, dU12, b11, b12,
                       W21, U21, dW21, dU21, W22, dW22, U22, dU22, b21, b22,
                       out);
}